// Round 1
// baseline (2067.795 us; speedup 1.0000x reference)
//
#include <hip/hip_runtime.h>
#include <math.h>

#define S_LEN 2048
#define HID   768
#define NH    12
#define HD    64
#define WIN   128
#define NEGV  (-1e30f)

// ---------------------------------------------------------------------------
// GEMM: C[m][n] = dot(A[m][0:768], W[n][0:768]) + bias[n]
// A: [M=4096][768] row-major, W: [768][768] row-major (nn.Linear weight: out,in)
// BM=128, BN=64, BK=16; 256 threads; 8x4 micro-tile per thread.
// out_mode 0: out[m*768 + n]   (flat (B,S,H))
// out_mode 1: out[((b*12 + h)*2048 + s)*64 + d]  (B,nh,S,hd); h=n/64, d=n%64
// ---------------------------------------------------------------------------
__global__ __launch_bounds__(256) void gemm_bias(
    const float* __restrict__ A, const float* __restrict__ W,
    const float* __restrict__ bias, float* __restrict__ out, int out_mode)
{
    __shared__ float As[16][132];   // [k][m] transposed; 132 pad keeps 16B align
    __shared__ float Ws[16][68];    // [k][n] transposed

    const int tid = threadIdx.x;
    const int tx = tid & 15;
    const int ty = tid >> 4;
    const int m0 = blockIdx.x * 128;
    const int n0 = blockIdx.y * 64;

    float acc[8][4];
    #pragma unroll
    for (int i = 0; i < 8; i++)
        #pragma unroll
        for (int j = 0; j < 4; j++) acc[i][j] = 0.f;

    const int lrA = tid >> 1;          // 0..127
    const int lkA = (tid & 1) * 8;     // 0 / 8
    const int lrW = tid >> 2;          // 0..63
    const int lkW = (tid & 3) * 4;     // 0,4,8,12

    const float* Aptr = A + (size_t)(m0 + lrA) * HID + lkA;
    const float* Wptr = W + (size_t)(n0 + lrW) * HID + lkW;

    for (int k0 = 0; k0 < HID; k0 += 16) {
        float4 a0 = *(const float4*)(Aptr + k0);
        float4 a1 = *(const float4*)(Aptr + k0 + 4);
        float4 w0 = *(const float4*)(Wptr + k0);
        __syncthreads();   // previous iteration's reads complete
        As[lkA+0][lrA] = a0.x; As[lkA+1][lrA] = a0.y;
        As[lkA+2][lrA] = a0.z; As[lkA+3][lrA] = a0.w;
        As[lkA+4][lrA] = a1.x; As[lkA+5][lrA] = a1.y;
        As[lkA+6][lrA] = a1.z; As[lkA+7][lrA] = a1.w;
        Ws[lkW+0][lrW] = w0.x; Ws[lkW+1][lrW] = w0.y;
        Ws[lkW+2][lrW] = w0.z; Ws[lkW+3][lrW] = w0.w;
        __syncthreads();
        #pragma unroll
        for (int kk = 0; kk < 16; kk++) {
            float4 av0 = *(const float4*)&As[kk][ty*8];
            float4 av1 = *(const float4*)&As[kk][ty*8+4];
            float4 wv  = *(const float4*)&Ws[kk][tx*4];
            float a[8] = {av0.x,av0.y,av0.z,av0.w,av1.x,av1.y,av1.z,av1.w};
            float w[4] = {wv.x,wv.y,wv.z,wv.w};
            #pragma unroll
            for (int i = 0; i < 8; i++)
                #pragma unroll
                for (int j = 0; j < 4; j++)
                    acc[i][j] += a[i] * w[j];
        }
    }

    const float4 bv = *(const float4*)&bias[n0 + tx*4];
    if (out_mode == 0) {
        #pragma unroll
        for (int i = 0; i < 8; i++) {
            const int m = m0 + ty*8 + i;
            float4 o;
            o.x = acc[i][0] + bv.x; o.y = acc[i][1] + bv.y;
            o.z = acc[i][2] + bv.z; o.w = acc[i][3] + bv.w;
            *(float4*)&out[(size_t)m * HID + n0 + tx*4] = o;
        }
    } else {
        const int h  = n0 >> 6;      // BN=64 & n0%64==0 -> single head per block
        const int d0 = tx * 4;
        #pragma unroll
        for (int i = 0; i < 8; i++) {
            const int m = m0 + ty*8 + i;
            const int b = m >> 11;        // /2048
            const int s = m & 2047;
            float4 o;
            o.x = acc[i][0] + bv.x; o.y = acc[i][1] + bv.y;
            o.z = acc[i][2] + bv.z; o.w = acc[i][3] + bv.w;
            *(float4*)&out[(((size_t)b*NH + h)*S_LEN + s)*HD + d0] = o;
        }
    }
}

// ---------------------------------------------------------------------------
// Flash-style attention over precomputed Q,K,V in (B,nh,S,hd) layout.
// Grid: (S/64, NH, B); 256 threads; per block: 64 q-rows x full key sweep.
// Mask semantics replicate reference exactly: masked score := -1e30 (finite),
// so an all-masked prefix yields uniform weights that later rescale to 0.
// Writes AO in (B,S,H) flat layout so the output GEMM is a plain GEMM.
// ---------------------------------------------------------------------------
__global__ __launch_bounds__(256) void attn_fwd(
    const float* __restrict__ Q, const float* __restrict__ K,
    const float* __restrict__ V, const int* __restrict__ amask,
    const int* __restrict__ gmask, float* __restrict__ AO)
{
    __shared__ float Qs[64][68];    // [row][d], pre-scaled by 1/8
    __shared__ float KVs[64][68];   // scores phase: K^T [d][key]; PV phase: V [key][d]
    __shared__ float Ps[64][68];    // probabilities [row][key]
    __shared__ int   s_am[64];      // key attention_mask
    __shared__ int   s_gk[64];      // key global flag

    const int tid = threadIdx.x;
    const int tx = tid & 15;
    const int ty = tid >> 4;
    const int b  = blockIdx.z;
    const int h  = blockIdx.y;
    const int q0 = blockIdx.x * 64;

    const size_t bh = ((size_t)b * NH + h) * S_LEN;

    // ---- load Q tile (scaled by 1/sqrt(64) = 0.125, exact) ----
    {
        const int r  = tid >> 2;            // 0..63
        const int d0 = (tid & 3) * 16;
        const float* qp = Q + (bh + q0 + r) * HD + d0;
        #pragma unroll
        for (int u = 0; u < 4; u++) {
            float4 qv = *(const float4*)(qp + u*4);
            qv.x *= 0.125f; qv.y *= 0.125f; qv.z *= 0.125f; qv.w *= 0.125f;
            *(float4*)&Qs[r][d0 + u*4] = qv;
        }
    }
    int gq[4];
    #pragma unroll
    for (int i = 0; i < 4; i++)
        gq[i] = gmask[(size_t)b * S_LEN + q0 + ty*4 + i];

    float m_i[4], l_i[4], acc[4][4];
    #pragma unroll
    for (int i = 0; i < 4; i++) {
        m_i[i] = NEGV; l_i[i] = 0.f;
        #pragma unroll
        for (int j = 0; j < 4; j++) acc[i][j] = 0.f;
    }

    for (int kt = 0; kt < S_LEN/64; kt++) {
        const int k0 = kt * 64;
        __syncthreads();   // previous PV done reading KVs(V) & Ps
        // ---- load K tile transposed + key flags ----
        {
            const int c  = tid >> 2;
            const int d0 = (tid & 3) * 16;
            const float* kp = K + (bh + k0 + c) * HD + d0;
            #pragma unroll
            for (int u = 0; u < 4; u++) {
                float4 kv = *(const float4*)(kp + u*4);
                KVs[d0+u*4+0][c] = kv.x;
                KVs[d0+u*4+1][c] = kv.y;
                KVs[d0+u*4+2][c] = kv.z;
                KVs[d0+u*4+3][c] = kv.w;
            }
            if (tid < 64) {
                s_am[tid] = amask[(size_t)b * S_LEN + k0 + tid];
                s_gk[tid] = gmask[(size_t)b * S_LEN + k0 + tid];
            }
        }
        __syncthreads();
        // ---- scores: s[i][j] = Qs[row] . K[col] (Q pre-scaled) ----
        float s[4][4];
        #pragma unroll
        for (int i = 0; i < 4; i++)
            #pragma unroll
            for (int j = 0; j < 4; j++) s[i][j] = 0.f;
        for (int k = 0; k < HD; k += 4) {
            float4 q0v = *(const float4*)&Qs[ty*4+0][k];
            float4 q1v = *(const float4*)&Qs[ty*4+1][k];
            float4 q2v = *(const float4*)&Qs[ty*4+2][k];
            float4 q3v = *(const float4*)&Qs[ty*4+3][k];
            float4 c0 = *(const float4*)&KVs[k+0][tx*4];
            float4 c1 = *(const float4*)&KVs[k+1][tx*4];
            float4 c2 = *(const float4*)&KVs[k+2][tx*4];
            float4 c3 = *(const float4*)&KVs[k+3][tx*4];
            const float qa[4][4] = {
                {q0v.x,q0v.y,q0v.z,q0v.w}, {q1v.x,q1v.y,q1v.z,q1v.w},
                {q2v.x,q2v.y,q2v.z,q2v.w}, {q3v.x,q3v.y,q3v.z,q3v.w}};
            const float cb[4][4] = {
                {c0.x,c0.y,c0.z,c0.w}, {c1.x,c1.y,c1.z,c1.w},
                {c2.x,c2.y,c2.z,c2.w}, {c3.x,c3.y,c3.z,c3.w}};
            #pragma unroll
            for (int i = 0; i < 4; i++)
                #pragma unroll
                for (int j = 0; j < 4; j++) {
                    s[i][j] += qa[i][0]*cb[0][j];
                    s[i][j] += qa[i][1]*cb[1][j];
                    s[i][j] += qa[i][2]*cb[2][j];
                    s[i][j] += qa[i][3]*cb[3][j];
                }
        }
        // ---- mask + online softmax (row groups = 16 consecutive lanes) ----
        #pragma unroll
        for (int i = 0; i < 4; i++) {
            const int qi = q0 + ty*4 + i;
            float mloc = NEGV;
            #pragma unroll
            for (int j = 0; j < 4; j++) {
                const int cj = k0 + tx*4 + j;
                int dd = qi - cj; if (dd < 0) dd = -dd;
                const bool ok = s_am[tx*4+j] && ((dd <= WIN) || gq[i] || s_gk[tx*4+j]);
                if (!ok) s[i][j] = NEGV;
                mloc = fmaxf(mloc, s[i][j]);
            }
            #pragma unroll
            for (int off = 1; off < 16; off <<= 1)
                mloc = fmaxf(mloc, __shfl_xor(mloc, off, 16));
            const float mnew = fmaxf(m_i[i], mloc);
            const float sc   = __expf(m_i[i] - mnew);
            float p[4], lloc = 0.f;
            #pragma unroll
            for (int j = 0; j < 4; j++) { p[j] = __expf(s[i][j] - mnew); lloc += p[j]; }
            #pragma unroll
            for (int off = 1; off < 16; off <<= 1)
                lloc += __shfl_xor(lloc, off, 16);
            l_i[i] = l_i[i] * sc + lloc;
            m_i[i] = mnew;
            #pragma unroll
            for (int j = 0; j < 4; j++) acc[i][j] *= sc;
            float4 pv = {p[0], p[1], p[2], p[3]};
            *(float4*)&Ps[ty*4+i][tx*4] = pv;
        }
        __syncthreads();   // Ps written; KVs(K) reads done
        // ---- load V tile (natural [key][d]) ----
        {
            const int r  = tid >> 2;
            const int d0 = (tid & 3) * 16;
            const float* vp = V + (bh + k0 + r) * HD + d0;
            #pragma unroll
            for (int u = 0; u < 4; u++)
                *(float4*)&KVs[r][d0 + u*4] = *(const float4*)(vp + u*4);
        }
        __syncthreads();
        // ---- PV accumulate ----
        for (int k = 0; k < 64; k += 4) {
            float4 p0 = *(const float4*)&Ps[ty*4+0][k];
            float4 p1 = *(const float4*)&Ps[ty*4+1][k];
            float4 p2 = *(const float4*)&Ps[ty*4+2][k];
            float4 p3 = *(const float4*)&Ps[ty*4+3][k];
            float4 v0 = *(const float4*)&KVs[k+0][tx*4];
            float4 v1 = *(const float4*)&KVs[k+1][tx*4];
            float4 v2 = *(const float4*)&KVs[k+2][tx*4];
            float4 v3 = *(const float4*)&KVs[k+3][tx*4];
            const float pa[4][4] = {
                {p0.x,p0.y,p0.z,p0.w}, {p1.x,p1.y,p1.z,p1.w},
                {p2.x,p2.y,p2.z,p2.w}, {p3.x,p3.y,p3.z,p3.w}};
            const float vb[4][4] = {
                {v0.x,v0.y,v0.z,v0.w}, {v1.x,v1.y,v1.z,v1.w},
                {v2.x,v2.y,v2.z,v2.w}, {v3.x,v3.y,v3.z,v3.w}};
            #pragma unroll
            for (int i = 0; i < 4; i++)
                #pragma unroll
                for (int j = 0; j < 4; j++) {
                    acc[i][j] += pa[i][0]*vb[0][j];
                    acc[i][j] += pa[i][1]*vb[1][j];
                    acc[i][j] += pa[i][2]*vb[2][j];
                    acc[i][j] += pa[i][3]*vb[3][j];
                }
        }
    }

    // ---- epilogue: normalize and write (B,S,H) flat ----
    #pragma unroll
    for (int i = 0; i < 4; i++) {
        const float inv = 1.f / l_i[i];
        const int row = q0 + ty*4 + i;
        float4 o;
        o.x = acc[i][0]*inv; o.y = acc[i][1]*inv;
        o.z = acc[i][2]*inv; o.w = acc[i][3]*inv;
        *(float4*)&AO[((size_t)b*S_LEN + row)*HID + h*HD + tx*4] = o;
    }
}

// ---------------------------------------------------------------------------
extern "C" void kernel_launch(void* const* d_in, const int* in_sizes, int n_in,
                              void* d_out, int out_size, void* d_ws, size_t ws_size,
                              hipStream_t stream)
{
    const float* hidden = (const float*)d_in[0];
    const int*   amask  = (const int*)d_in[1];
    const int*   gmask  = (const int*)d_in[2];
    const float* Wq = (const float*)d_in[3];
    const float* bq = (const float*)d_in[4];
    const float* Wk = (const float*)d_in[5];
    const float* bk = (const float*)d_in[6];
    const float* Wv = (const float*)d_in[7];
    const float* bv = (const float*)d_in[8];
    const float* Wo = (const float*)d_in[9];
    const float* bo = (const float*)d_in[10];
    float* out = (float*)d_out;

    float* ws = (float*)d_ws;
    const size_t per = (size_t)2 * S_LEN * HID;   // 3,145,728 floats
    float* Qw  = ws;
    float* Kw  = ws + per;
    float* Vw  = ws + 2*per;
    float* AOw = ws + 3*per;

    dim3 gg(4096/128, HID/64);   // (32, 12)
    gemm_bias<<<gg, 256, 0, stream>>>(hidden, Wq, bq, Qw, 1);
    gemm_bias<<<gg, 256, 0, stream>>>(hidden, Wk, bk, Kw, 1);
    gemm_bias<<<gg, 256, 0, stream>>>(hidden, Wv, bv, Vw, 1);

    dim3 ga(S_LEN/64, NH, 2);    // (32, 12, 2)
    attn_fwd<<<ga, 256, 0, stream>>>(Qw, Kw, Vw, amask, gmask, AOw);

    gemm_bias<<<gg, 256, 0, stream>>>(AOw, Wo, bo, out, 0);
}

// Round 2
// 444.522 us; speedup vs baseline: 4.6517x; 4.6517x over previous
//
#include <hip/hip_runtime.h>
#include <math.h>

#define S_LEN 2048
#define HID   768
#define NH    12
#define HD    64
#define WIN   128
#define NEGV  (-1e30f)

typedef __attribute__((ext_vector_type(8))) short short8v;
typedef __attribute__((ext_vector_type(4))) float float4v;

__device__ __forceinline__ unsigned short f2bf(float f) {
    union { float f; unsigned int u; } c; c.f = f;
    unsigned int u = c.u + 0x7FFFu + ((c.u >> 16) & 1u);
    return (unsigned short)(u >> 16);
}

__device__ __forceinline__ short8v cvt8(float4 a, float4 b) {
    short8v t;
    t[0]=(short)f2bf(a.x); t[1]=(short)f2bf(a.y); t[2]=(short)f2bf(a.z); t[3]=(short)f2bf(a.w);
    t[4]=(short)f2bf(b.x); t[5]=(short)f2bf(b.y); t[6]=(short)f2bf(b.z); t[7]=(short)f2bf(b.w);
    return t;
}

// ---------------------------------------------------------------------------
// f32 GEMM (unchanged from round 1 — known good).
// ---------------------------------------------------------------------------
__global__ __launch_bounds__(256) void gemm_bias(
    const float* __restrict__ A, const float* __restrict__ W,
    const float* __restrict__ bias, float* __restrict__ out, int out_mode)
{
    __shared__ float As[16][132];
    __shared__ float Ws[16][68];

    const int tid = threadIdx.x;
    const int tx = tid & 15;
    const int ty = tid >> 4;
    const int m0 = blockIdx.x * 128;
    const int n0 = blockIdx.y * 64;

    float acc[8][4];
    #pragma unroll
    for (int i = 0; i < 8; i++)
        #pragma unroll
        for (int j = 0; j < 4; j++) acc[i][j] = 0.f;

    const int lrA = tid >> 1;
    const int lkA = (tid & 1) * 8;
    const int lrW = tid >> 2;
    const int lkW = (tid & 3) * 4;

    const float* Aptr = A + (size_t)(m0 + lrA) * HID + lkA;
    const float* Wptr = W + (size_t)(n0 + lrW) * HID + lkW;

    for (int k0 = 0; k0 < HID; k0 += 16) {
        float4 a0 = *(const float4*)(Aptr + k0);
        float4 a1 = *(const float4*)(Aptr + k0 + 4);
        float4 w0 = *(const float4*)(Wptr + k0);
        __syncthreads();
        As[lkA+0][lrA] = a0.x; As[lkA+1][lrA] = a0.y;
        As[lkA+2][lrA] = a0.z; As[lkA+3][lrA] = a0.w;
        As[lkA+4][lrA] = a1.x; As[lkA+5][lrA] = a1.y;
        As[lkA+6][lrA] = a1.z; As[lkA+7][lrA] = a1.w;
        Ws[lkW+0][lrW] = w0.x; Ws[lkW+1][lrW] = w0.y;
        Ws[lkW+2][lrW] = w0.z; Ws[lkW+3][lrW] = w0.w;
        __syncthreads();
        #pragma unroll
        for (int kk = 0; kk < 16; kk++) {
            float4 av0 = *(const float4*)&As[kk][ty*8];
            float4 av1 = *(const float4*)&As[kk][ty*8+4];
            float4 wv  = *(const float4*)&Ws[kk][tx*4];
            float a[8] = {av0.x,av0.y,av0.z,av0.w,av1.x,av1.y,av1.z,av1.w};
            float w[4] = {wv.x,wv.y,wv.z,wv.w};
            #pragma unroll
            for (int i = 0; i < 8; i++)
                #pragma unroll
                for (int j = 0; j < 4; j++)
                    acc[i][j] += a[i] * w[j];
        }
    }

    const float4 bv = *(const float4*)&bias[n0 + tx*4];
    if (out_mode == 0) {
        #pragma unroll
        for (int i = 0; i < 8; i++) {
            const int m = m0 + ty*8 + i;
            float4 o;
            o.x = acc[i][0] + bv.x; o.y = acc[i][1] + bv.y;
            o.z = acc[i][2] + bv.z; o.w = acc[i][3] + bv.w;
            *(float4*)&out[(size_t)m * HID + n0 + tx*4] = o;
        }
    } else {
        const int h  = n0 >> 6;
        const int d0 = tx * 4;
        #pragma unroll
        for (int i = 0; i < 8; i++) {
            const int m = m0 + ty*8 + i;
            const int b = m >> 11;
            const int s = m & 2047;
            float4 o;
            o.x = acc[i][0] + bv.x; o.y = acc[i][1] + bv.y;
            o.z = acc[i][2] + bv.z; o.w = acc[i][3] + bv.w;
            *(float4*)&out[(((size_t)b*NH + h)*S_LEN + s)*HD + d0] = o;
        }
    }
}

// ---------------------------------------------------------------------------
// V (B,nh,S,hd) f32  ->  Vt (B,nh,hd,S) bf16, 64x64 LDS tiles, coalesced.
// ---------------------------------------------------------------------------
__global__ __launch_bounds__(256) void transpose_v(
    const float* __restrict__ V, unsigned short* __restrict__ Vt)
{
    __shared__ float T[64][65];
    const int bh = blockIdx.y;
    const int s0 = blockIdx.x * 64;
    const int tid = threadIdx.x;
    {
        const int r = tid >> 2, c = (tid & 3) * 16;
        const float* vp = V + ((size_t)bh*S_LEN + s0 + r)*HD + c;
        #pragma unroll
        for (int u = 0; u < 4; u++) {
            float4 f = *(const float4*)(vp + u*4);
            T[r][c+u*4+0]=f.x; T[r][c+u*4+1]=f.y;
            T[r][c+u*4+2]=f.z; T[r][c+u*4+3]=f.w;
        }
    }
    __syncthreads();
    {
        const int d = tid >> 2, sg = (tid & 3) * 16;
        unsigned short buf[16];
        #pragma unroll
        for (int u = 0; u < 16; u++) buf[u] = f2bf(T[sg+u][d]);
        unsigned short* op = Vt + ((size_t)bh*HD + d)*S_LEN + s0 + sg;
        *(uint4*)(op)   = *(uint4*)&buf[0];
        *(uint4*)(op+8) = *(uint4*)&buf[8];
    }
}

// ---------------------------------------------------------------------------
// Flash attention, bf16 MFMA 16x16x32, f32 accum.
// Block: 256 thr = 4 waves; wave w owns q-rows [q0+16w, q0+16w+16).
// Per 64-key tile: K staged bf16 LDS (XOR-swizzled rows), Vt staged bf16 LDS.
// A-frag (Q/P): lane l -> row=l&15, k=8*(l>>4)+i (+32*ks).
// B-frag (K/V): lane l -> col=l&15, k=8*(l>>4)+i (+32*ks).
// C/D: col=l&15, row=(l>>4)*4+reg   [guide §3, m89-verified].
// ---------------------------------------------------------------------------
__global__ __launch_bounds__(256) void attn_mfma(
    const float* __restrict__ Q, const float* __restrict__ K,
    const unsigned short* __restrict__ Vt, const int* __restrict__ amask,
    const int* __restrict__ gmask, float* __restrict__ AO)
{
    __shared__ __align__(16) unsigned short Ks[64*64];   // [key][d] swizzled
    __shared__ __align__(16) unsigned short Vs[64*64];   // [d][key] swizzled
    __shared__ __align__(16) unsigned short Ps[4*16*64]; // per-wave [q][key] swizzled
    __shared__ int s_am[64];
    __shared__ int s_gk[64];

    const int tid = threadIdx.x;
    const int w  = tid >> 6;
    const int l  = tid & 63;
    const int lx = l & 15;
    const int lg = l >> 4;
    const int b  = blockIdx.z;
    const int h  = blockIdx.y;
    const int q0 = blockIdx.x * 64;
    const size_t bh = ((size_t)b*NH + h) * S_LEN;

    // ---- Q fragments in registers, pre-scaled by 1/8 ----
    short8v aq[2];
    {
        const int qrow = q0 + w*16 + lx;
        const float* qp = Q + (bh + qrow)*HD + 8*lg;
        #pragma unroll
        for (int ks = 0; ks < 2; ks++) {
            float4 f0 = *(const float4*)(qp + 32*ks);
            float4 f1 = *(const float4*)(qp + 32*ks + 4);
            f0.x*=0.125f; f0.y*=0.125f; f0.z*=0.125f; f0.w*=0.125f;
            f1.x*=0.125f; f1.y*=0.125f; f1.z*=0.125f; f1.w*=0.125f;
            aq[ks] = cvt8(f0, f1);
        }
    }
    int gqf[4];
    #pragma unroll
    for (int r = 0; r < 4; r++)
        gqf[r] = gmask[(size_t)b*S_LEN + q0 + w*16 + lg*4 + r];

    float m_i[4], l_i[4];
    float4v o_acc[4];
    const float4v fz = {0.f, 0.f, 0.f, 0.f};
    #pragma unroll
    for (int r = 0; r < 4; r++) { m_i[r] = NEGV; l_i[r] = 0.f; }
    #pragma unroll
    for (int db = 0; db < 4; db++) o_acc[db] = fz;

    const int str = tid >> 2;        // staging row 0..63
    const int stc = tid & 3;         // staging chunk
    const int rb  = str * 128;       // row byte base
    const int sw  = (str & 7) << 4;  // row swizzle
    const float* Kbase = K + bh * HD;
    const unsigned short* Vbase = Vt + (size_t)(b*NH + h) * HD * S_LEN;

    for (int kt = 0; kt < S_LEN/64; kt++) {
        const int k0 = kt * 64;
        __syncthreads();
        // ---- stage K tile: f32 -> bf16, swizzled ----
        {
            const float* kp = Kbase + (size_t)(k0 + str)*HD + stc*16;
            float4 f0 = *(const float4*)(kp);
            float4 f1 = *(const float4*)(kp + 4);
            float4 f2 = *(const float4*)(kp + 8);
            float4 f3 = *(const float4*)(kp + 12);
            *(short8v*)((char*)Ks + rb + ((stc*32)      ^ sw)) = cvt8(f0, f1);
            *(short8v*)((char*)Ks + rb + ((stc*32 + 16) ^ sw)) = cvt8(f2, f3);
        }
        // ---- stage Vt tile (already bf16), swizzled ----
        {
            const unsigned short* vp = Vbase + (size_t)str*S_LEN + k0 + stc*16;
            uint4 u0 = *(const uint4*)(vp);
            uint4 u1 = *(const uint4*)(vp + 8);
            *(uint4*)((char*)Vs + rb + ((stc*32)      ^ sw)) = u0;
            *(uint4*)((char*)Vs + rb + ((stc*32 + 16) ^ sw)) = u1;
        }
        if (tid < 64) {
            s_am[tid] = amask[(size_t)b*S_LEN + k0 + tid];
            s_gk[tid] = gmask[(size_t)b*S_LEN + k0 + tid];
        }
        __syncthreads();

        // ---- QK^T: 4 key-blocks x 2 k-steps ----
        float4v sacc[4];
        #pragma unroll
        for (int kb = 0; kb < 4; kb++) sacc[kb] = fz;
        #pragma unroll
        for (int kb = 0; kb < 4; kb++) {
            const int key = kb*16 + lx;
            const int ksw = (key & 7) << 4;
            #pragma unroll
            for (int ks = 0; ks < 2; ks++) {
                short8v bk = *(const short8v*)((char*)Ks + key*128 + ((16*lg + 64*ks) ^ ksw));
                sacc[kb] = __builtin_amdgcn_mfma_f32_16x16x32_bf16(aq[ks], bk, sacc[kb], 0, 0, 0);
            }
        }

        // ---- mask + online softmax (C-layout: row=lg*4+r, col=kb*16+lx) ----
        int amk[4], gkk[4];
        #pragma unroll
        for (int kb = 0; kb < 4; kb++) {
            amk[kb] = s_am[kb*16 + lx];
            gkk[kb] = s_gk[kb*16 + lx];
        }
        #pragma unroll
        for (int r = 0; r < 4; r++) {
            const int qi = q0 + w*16 + lg*4 + r;
            float sv[4];
            float mloc = NEGV;
            #pragma unroll
            for (int kb = 0; kb < 4; kb++) {
                const int kj = k0 + kb*16 + lx;
                int dd = qi - kj; dd = dd < 0 ? -dd : dd;
                const bool ok = amk[kb] && ((dd <= WIN) || gqf[r] || gkk[kb]);
                sv[kb] = ok ? sacc[kb][r] : NEGV;
                mloc = fmaxf(mloc, sv[kb]);
            }
            #pragma unroll
            for (int off = 1; off < 16; off <<= 1)
                mloc = fmaxf(mloc, __shfl_xor(mloc, off, 16));
            const float mnew = fmaxf(m_i[r], mloc);
            const float sc = __expf(m_i[r] - mnew);
            float p[4], lloc = 0.f;
            #pragma unroll
            for (int kb = 0; kb < 4; kb++) { p[kb] = __expf(sv[kb] - mnew); lloc += p[kb]; }
            #pragma unroll
            for (int off = 1; off < 16; off <<= 1)
                lloc += __shfl_xor(lloc, off, 16);
            l_i[r] = l_i[r]*sc + lloc;
            m_i[r] = mnew;
            #pragma unroll
            for (int db = 0; db < 4; db++) o_acc[db][r] *= sc;
            // write P (bf16) to this wave's region, swizzled [q][key]
            const int qrow = lg*4 + r;
            const int qsw = (qrow & 7) << 4;
            #pragma unroll
            for (int kb = 0; kb < 4; kb++) {
                *((unsigned short*)((char*)Ps + w*2048 + qrow*128 + (((kb*16 + lx)*2) ^ qsw))) =
                    f2bf(p[kb]);
            }
        }
        __syncthreads();

        // ---- PV: O[16q][64d] += P[16q][64k] * V[64k][64d] ----
        #pragma unroll
        for (int ks = 0; ks < 2; ks++) {
            short8v pa = *(const short8v*)((char*)Ps + w*2048 + lx*128 +
                                           ((16*lg + 64*ks) ^ ((lx & 7) << 4)));
            #pragma unroll
            for (int db = 0; db < 4; db++) {
                const int drow = db*16 + lx;
                short8v bv = *(const short8v*)((char*)Vs + drow*128 +
                                               ((16*lg + 64*ks) ^ ((drow & 7) << 4)));
                o_acc[db] = __builtin_amdgcn_mfma_f32_16x16x32_bf16(pa, bv, o_acc[db], 0, 0, 0);
            }
        }
    }

    // ---- epilogue: normalize, write AO (B,S,H) f32 ----
    #pragma unroll
    for (int r = 0; r < 4; r++) {
        const float inv = 1.f / l_i[r];
        const int row = q0 + w*16 + lg*4 + r;
        float* op = AO + ((size_t)b*S_LEN + row)*HID + h*HD + lx;
        #pragma unroll
        for (int db = 0; db < 4; db++) op[db*16] = o_acc[db][r] * inv;
    }
}

// ---------------------------------------------------------------------------
extern "C" void kernel_launch(void* const* d_in, const int* in_sizes, int n_in,
                              void* d_out, int out_size, void* d_ws, size_t ws_size,
                              hipStream_t stream)
{
    const float* hidden = (const float*)d_in[0];
    const int*   amask  = (const int*)d_in[1];
    const int*   gmask  = (const int*)d_in[2];
    const float* Wq = (const float*)d_in[3];
    const float* bq = (const float*)d_in[4];
    const float* Wk = (const float*)d_in[5];
    const float* bk = (const float*)d_in[6];
    const float* Wv = (const float*)d_in[7];
    const float* bv = (const float*)d_in[8];
    const float* Wo = (const float*)d_in[9];
    const float* bo = (const float*)d_in[10];
    float* out = (float*)d_out;

    float* ws = (float*)d_ws;
    const size_t per = (size_t)2 * S_LEN * HID;   // 3,145,728 floats
    float* Qw  = ws;
    float* Kw  = ws + per;
    float* Vw  = ws + 2*per;
    float* AOw = ws + 3*per;
    unsigned short* Vtw = (unsigned short*)(ws + 4*per);   // 6.3 MB bf16

    dim3 gg(4096/128, HID/64);
    gemm_bias<<<gg, 256, 0, stream>>>(hidden, Wq, bq, Qw, 1);
    gemm_bias<<<gg, 256, 0, stream>>>(hidden, Wk, bk, Kw, 1);
    gemm_bias<<<gg, 256, 0, stream>>>(hidden, Wv, bv, Vw, 1);

    transpose_v<<<dim3(S_LEN/64, 2*NH), 256, 0, stream>>>(Vw, Vtw);

    dim3 ga(S_LEN/64, NH, 2);
    attn_mfma<<<ga, 256, 0, stream>>>(Qw, Kw, Vtw, amask, gmask, AOw);

    gemm_bias<<<gg, 256, 0, stream>>>(AOw, Wo, bo, out, 0);
}

// Round 4
// 167.034 us; speedup vs baseline: 12.3795x; 2.6613x over previous
//
#include <hip/hip_runtime.h>
#include <math.h>

#define S_LEN 2048
#define HID   768
#define NH    12
#define HD    64
#define WIN   128
#define NEGV  (-1e30f)

typedef __attribute__((ext_vector_type(8))) short short8v;
typedef __attribute__((ext_vector_type(4))) float float4v;
typedef unsigned short u16;

__device__ __forceinline__ u16 f2bf(float f) {
    union { float f; unsigned int u; } c; c.f = f;
    unsigned int u = c.u + 0x7FFFu + ((c.u >> 16) & 1u);
    return (u16)(u >> 16);
}

__device__ __forceinline__ short8v cvt8(float4 a, float4 b) {
    short8v t;
    t[0]=(short)f2bf(a.x); t[1]=(short)f2bf(a.y); t[2]=(short)f2bf(a.z); t[3]=(short)f2bf(a.w);
    t[4]=(short)f2bf(b.x); t[5]=(short)f2bf(b.y); t[6]=(short)f2bf(b.z); t[7]=(short)f2bf(b.w);
    return t;
}

__device__ __forceinline__ void gload_lds16(const void* g, void* l) {
    __builtin_amdgcn_global_load_lds(
        (const __attribute__((address_space(1))) unsigned int*)g,
        (__attribute__((address_space(3))) unsigned int*)l, 16, 0, 0);
}

// ---------------------------------------------------------------------------
// Convert hidden + 4 weights to bf16 (Wq scaled by 0.125 = 1/sqrt(HD), exact).
// ---------------------------------------------------------------------------
__global__ __launch_bounds__(256) void convert_inputs(
    const float* __restrict__ hidden, const float* __restrict__ Wq,
    const float* __restrict__ Wk, const float* __restrict__ Wv,
    const float* __restrict__ Wo, u16* __restrict__ hbf, u16* __restrict__ w4)
{
    const int y = blockIdx.y;
    const float* src; u16* dst; int n; float scale = 1.f;
    if (y == 0) { src = hidden; dst = hbf; n = 4096*HID; }
    else {
        src = (y==1) ? Wq : (y==2) ? Wk : (y==3) ? Wv : Wo;
        dst = w4 + (size_t)(y-1)*HID*HID;
        n = HID*HID;
        if (y == 1) scale = 0.125f;
    }
    const int idx = (blockIdx.x*256 + threadIdx.x) * 8;
    if (idx >= n) return;
    float4 f0 = *(const float4*)(src + idx);
    float4 f1 = *(const float4*)(src + idx + 4);
    f0.x*=scale; f0.y*=scale; f0.z*=scale; f0.w*=scale;
    f1.x*=scale; f1.y*=scale; f1.z*=scale; f1.w*=scale;
    *(short8v*)(dst + idx) = cvt8(f0, f1);
}

// ---------------------------------------------------------------------------
// bf16 MFMA GEMM (m97 structure). C[m][n] = sum_k A[m][k]*W[n][k] + bias[n].
// mode 0: z=blockIdx.z in {0,1,2} -> Wq',Wk,Wv; out bf16 (B,nh,S,hd) at
//         obf + z*NTOK  (BUGFIX vs round 3: z-offset was missing).
// mode 1: Wo (z=3); out f32 flat (B,S,H).
// ---------------------------------------------------------------------------
__global__ __launch_bounds__(256) void gemm_mfma(
    const u16* __restrict__ A, const u16* __restrict__ W4,
    const float* __restrict__ bA, const float* __restrict__ bB,
    const float* __restrict__ bC, u16* __restrict__ obf,
    float* __restrict__ of32, int mode)
{
    __shared__ __align__(16) u16 As[128*32];
    __shared__ __align__(16) u16 Bs[128*32];

    const int tid = threadIdx.x;
    const int w = tid >> 6, l = tid & 63;
    const int lx = l & 15, lg = l >> 4;
    const int wr = w >> 1, wc = w & 1;
    const int m0 = blockIdx.x * 128, n0 = blockIdx.y * 128;
    const int z = (mode == 0) ? blockIdx.z : 3;
    const float* bias = (mode == 1) ? bA : (z == 0 ? bA : (z == 1 ? bB : bC));
    const float bscale = (mode == 0 && z == 0) ? 0.125f : 1.0f;
    const u16* Wp = W4 + (size_t)z * (HID*HID);
    u16* obf_z = (mode == 0) ? (obf + (size_t)z * ((size_t)2*S_LEN*HID)) : obf;

    float4v acc[4][4];
    const float4v fz = {0.f,0.f,0.f,0.f};
    #pragma unroll
    for (int i = 0; i < 4; i++)
        #pragma unroll
        for (int j = 0; j < 4; j++) acc[i][j] = fz;

    for (int kt = 0; kt < HID/32; kt++) {
        const int k0 = kt * 32;
        __syncthreads();
        #pragma unroll
        for (int rnd = 0; rnd < 2; rnd++) {
            const int ch  = rnd*256 + w*64 + l;   // chunk id 0..511
            const int row = ch >> 2, kc = ch & 3;
            gload_lds16(A  + (size_t)(m0+row)*HID + k0 + kc*8,
                        As + (size_t)(rnd*256 + w*64)*8);
            gload_lds16(Wp + (size_t)(n0+row)*HID + k0 + kc*8,
                        Bs + (size_t)(rnd*256 + w*64)*8);
        }
        __syncthreads();
        short8v af[4], bfr[4];
        #pragma unroll
        for (int i = 0; i < 4; i++) {
            af[i]  = *(const short8v*)(As + (wr*64 + i*16 + lx)*32 + lg*8);
            bfr[i] = *(const short8v*)(Bs + (wc*64 + i*16 + lx)*32 + lg*8);
        }
        #pragma unroll
        for (int i = 0; i < 4; i++)
            #pragma unroll
            for (int j = 0; j < 4; j++)
                acc[i][j] = __builtin_amdgcn_mfma_f32_16x16x32_bf16(af[i], bfr[j], acc[i][j], 0, 0, 0);
    }

    #pragma unroll
    for (int j = 0; j < 4; j++) {
        const int col = n0 + wc*64 + j*16 + lx;
        const float bval = bias[col] * bscale;
        const int hh = col >> 6, d = col & 63;
        #pragma unroll
        for (int i = 0; i < 4; i++) {
            const int rbase = m0 + wr*64 + i*16 + lg*4;
            #pragma unroll
            for (int r = 0; r < 4; r++) {
                const int m = rbase + r;
                const float v = acc[i][j][r] + bval;
                if (mode == 0) {
                    const int bb = m >> 11, s = m & 2047;
                    obf_z[(((size_t)bb*NH + hh)*S_LEN + s)*HD + d] = f2bf(v);
                } else {
                    of32[(size_t)m*HID + col] = v;
                }
            }
        }
    }
}

// ---------------------------------------------------------------------------
// V (B,nh,S,hd) bf16 -> Vt (B,nh,hd,S) bf16. 64x64 tiles via LDS.
// ---------------------------------------------------------------------------
__global__ __launch_bounds__(256) void transpose_v(
    const u16* __restrict__ V, u16* __restrict__ Vt)
{
    __shared__ u16 T[64][65];
    const int bh = blockIdx.y;
    const int s0 = blockIdx.x * 64;
    const int tid = threadIdx.x;
    {
        const int r = tid >> 2, c = (tid & 3) * 16;
        const u16* vp = V + ((size_t)bh*S_LEN + s0 + r)*HD + c;
        uint4 u0 = *(const uint4*)(vp);
        uint4 u1 = *(const uint4*)(vp + 8);
        const u16* b0 = (const u16*)&u0;
        const u16* b1 = (const u16*)&u1;
        #pragma unroll
        for (int u = 0; u < 8; u++) { T[r][c+u] = b0[u]; T[r][c+8+u] = b1[u]; }
    }
    __syncthreads();
    {
        const int d = tid >> 2, sg = (tid & 3) * 16;
        u16 buf[16];
        #pragma unroll
        for (int u = 0; u < 16; u++) buf[u] = T[sg+u][d];
        u16* op = Vt + ((size_t)bh*HD + d)*S_LEN + s0 + sg;
        *(uint4*)(op)   = *(uint4*)&buf[0];
        *(uint4*)(op+8) = *(uint4*)&buf[8];
    }
}

// ---------------------------------------------------------------------------
// Flash attention, bf16 MFMA 16x16x32, f32 accum. All-bf16 inputs.
// ---------------------------------------------------------------------------
__global__ __launch_bounds__(256) void attn_mfma(
    const u16* __restrict__ Q, const u16* __restrict__ K,
    const u16* __restrict__ Vt, const int* __restrict__ amask,
    const int* __restrict__ gmask, u16* __restrict__ AO)
{
    __shared__ __align__(16) u16 Ks[64*64];   // [key][d] swizzled
    __shared__ __align__(16) u16 Vs[64*64];   // [d][key] swizzled
    __shared__ __align__(16) u16 Ps[4*16*64]; // per-wave [q][key] swizzled
    __shared__ int s_am[64];
    __shared__ int s_gk[64];

    const int tid = threadIdx.x;
    const int w  = tid >> 6;
    const int l  = tid & 63;
    const int lx = l & 15;
    const int lg = l >> 4;
    const int b  = blockIdx.z;
    const int h  = blockIdx.y;
    const int q0 = blockIdx.x * 64;
    const size_t bh = ((size_t)b*NH + h) * S_LEN;

    short8v aq[2];
    {
        const u16* qp = Q + (bh + q0 + w*16 + lx)*HD + lg*8;
        aq[0] = *(const short8v*)(qp);
        aq[1] = *(const short8v*)(qp + 32);
    }
    int gqf[4];
    #pragma unroll
    for (int r = 0; r < 4; r++)
        gqf[r] = gmask[(size_t)b*S_LEN + q0 + w*16 + lg*4 + r];

    float m_i[4], l_i[4];
    float4v o_acc[4];
    const float4v fz = {0.f, 0.f, 0.f, 0.f};
    #pragma unroll
    for (int r = 0; r < 4; r++) { m_i[r] = NEGV; l_i[r] = 0.f; }
    #pragma unroll
    for (int db = 0; db < 4; db++) o_acc[db] = fz;

    const int str = tid >> 2;
    const int stc = tid & 3;
    const int rb  = str * 128;
    const int sw  = (str & 7) << 4;
    const u16* Kbase = K + bh * HD;
    const u16* Vbase = Vt + (size_t)(b*NH + h) * HD * S_LEN;

    for (int kt = 0; kt < S_LEN/64; kt++) {
        const int k0 = kt * 64;
        __syncthreads();
        {
            const u16* kp = Kbase + (size_t)(k0 + str)*HD + stc*16;
            uint4 u0 = *(const uint4*)(kp);
            uint4 u1 = *(const uint4*)(kp + 8);
            *(uint4*)((char*)Ks + rb + ((stc*32)      ^ sw)) = u0;
            *(uint4*)((char*)Ks + rb + ((stc*32 + 16) ^ sw)) = u1;
        }
        {
            const u16* vp = Vbase + (size_t)str*S_LEN + k0 + stc*16;
            uint4 u0 = *(const uint4*)(vp);
            uint4 u1 = *(const uint4*)(vp + 8);
            *(uint4*)((char*)Vs + rb + ((stc*32)      ^ sw)) = u0;
            *(uint4*)((char*)Vs + rb + ((stc*32 + 16) ^ sw)) = u1;
        }
        if (tid < 64) {
            s_am[tid] = amask[(size_t)b*S_LEN + k0 + tid];
            s_gk[tid] = gmask[(size_t)b*S_LEN + k0 + tid];
        }
        __syncthreads();

        float4v sacc[4];
        #pragma unroll
        for (int kb = 0; kb < 4; kb++) sacc[kb] = fz;
        #pragma unroll
        for (int kb = 0; kb < 4; kb++) {
            const int key = kb*16 + lx;
            const int ksw = (key & 7) << 4;
            #pragma unroll
            for (int ks = 0; ks < 2; ks++) {
                short8v bk = *(const short8v*)((char*)Ks + key*128 + ((16*lg + 64*ks) ^ ksw));
                sacc[kb] = __builtin_amdgcn_mfma_f32_16x16x32_bf16(aq[ks], bk, sacc[kb], 0, 0, 0);
            }
        }

        int amk[4], gkk[4];
        #pragma unroll
        for (int kb = 0; kb < 4; kb++) {
            amk[kb] = s_am[kb*16 + lx];
            gkk[kb] = s_gk[kb*16 + lx];
        }
        #pragma unroll
        for (int r = 0; r < 4; r++) {
            const int qi = q0 + w*16 + lg*4 + r;
            float sv[4];
            float mloc = NEGV;
            #pragma unroll
            for (int kb = 0; kb < 4; kb++) {
                const int kj = k0 + kb*16 + lx;
                int dd = qi - kj; dd = dd < 0 ? -dd : dd;
                const bool ok = amk[kb] && ((dd <= WIN) || gqf[r] || gkk[kb]);
                sv[kb] = ok ? sacc[kb][r] : NEGV;
                mloc = fmaxf(mloc, sv[kb]);
            }
            #pragma unroll
            for (int off = 1; off < 16; off <<= 1)
                mloc = fmaxf(mloc, __shfl_xor(mloc, off, 16));
            const float mnew = fmaxf(m_i[r], mloc);
            const float sc = __expf(m_i[r] - mnew);
            float p[4], lloc = 0.f;
            #pragma unroll
            for (int kb = 0; kb < 4; kb++) { p[kb] = __expf(sv[kb] - mnew); lloc += p[kb]; }
            #pragma unroll
            for (int off = 1; off < 16; off <<= 1)
                lloc += __shfl_xor(lloc, off, 16);
            l_i[r] = l_i[r]*sc + lloc;
            m_i[r] = mnew;
            #pragma unroll
            for (int db = 0; db < 4; db++) o_acc[db][r] *= sc;
            const int qrow = lg*4 + r;
            const int qsw = (qrow & 7) << 4;
            #pragma unroll
            for (int kb = 0; kb < 4; kb++) {
                *((u16*)((char*)Ps + w*2048 + qrow*128 + (((kb*16 + lx)*2) ^ qsw))) = f2bf(p[kb]);
            }
        }
        __syncthreads();

        #pragma unroll
        for (int ks = 0; ks < 2; ks++) {
            short8v pa = *(const short8v*)((char*)Ps + w*2048 + lx*128 +
                                           ((16*lg + 64*ks) ^ ((lx & 7) << 4)));
            #pragma unroll
            for (int db = 0; db < 4; db++) {
                const int drow = db*16 + lx;
                short8v bv = *(const short8v*)((char*)Vs + drow*128 +
                                               ((16*lg + 64*ks) ^ ((drow & 7) << 4)));
                o_acc[db] = __builtin_amdgcn_mfma_f32_16x16x32_bf16(pa, bv, o_acc[db], 0, 0, 0);
            }
        }
    }

    #pragma unroll
    for (int r = 0; r < 4; r++) {
        const float inv = 1.f / l_i[r];
        const int row = q0 + w*16 + lg*4 + r;
        u16* op = AO + ((size_t)b*S_LEN + row)*HID + h*HD + lx;
        #pragma unroll
        for (int db = 0; db < 4; db++) op[db*16] = f2bf(o_acc[db][r] * inv);
    }
}

// ---------------------------------------------------------------------------
extern "C" void kernel_launch(void* const* d_in, const int* in_sizes, int n_in,
                              void* d_out, int out_size, void* d_ws, size_t ws_size,
                              hipStream_t stream)
{
    const float* hidden = (const float*)d_in[0];
    const int*   amask  = (const int*)d_in[1];
    const int*   gmask  = (const int*)d_in[2];
    const float* Wq = (const float*)d_in[3];
    const float* bq = (const float*)d_in[4];
    const float* Wk = (const float*)d_in[5];
    const float* bk = (const float*)d_in[6];
    const float* Wv = (const float*)d_in[7];
    const float* bv = (const float*)d_in[8];
    const float* Wo = (const float*)d_in[9];
    const float* bo = (const float*)d_in[10];
    float* out = (float*)d_out;

    char* ws = (char*)d_ws;
    const size_t NTOK = (size_t)2 * S_LEN * HID;   // 3,145,728
    u16* hbf   = (u16*)(ws);
    u16* w4    = (u16*)(ws + 6291456);
    u16* qkvbf = (u16*)(ws + 11010048);            // 3 x NTOK
    u16* vtbf  = (u16*)(ws + 29884416);
    u16* aobf  = (u16*)(ws + 36175872);

    convert_inputs<<<dim3(1536, 5), 256, 0, stream>>>(hidden, Wq, Wk, Wv, Wo, hbf, w4);

    gemm_mfma<<<dim3(32, 6, 3), 256, 0, stream>>>(hbf, w4, bq, bk, bv, qkvbf, nullptr, 0);

    u16* Qbf = qkvbf;
    u16* Kbf = qkvbf + NTOK;
    u16* Vbf = qkvbf + 2*NTOK;

    transpose_v<<<dim3(S_LEN/64, 2*NH), 256, 0, stream>>>(Vbf, vtbf);

    attn_mfma<<<dim3(S_LEN/64, NH, 2), 256, 0, stream>>>(Qbf, Kbf, vtbf, amask, gmask, aobf);

    gemm_mfma<<<dim3(32, 6), 256, 0, stream>>>(aobf, w4, bo, nullptr, nullptr, nullptr, out, 1);
}

// Round 5
// 112.486 us; speedup vs baseline: 18.3827x; 1.4849x over previous
//
#include <hip/hip_runtime.h>
#include <math.h>

#define S_LEN 2048
#define HID   768
#define NH    12
#define HD    64
#define WIN   128
#define NEGV  (-1e30f)
#define QSCALE 0.1803368801111204f   /* 0.125 * log2(e): scores in log2 domain */

typedef __attribute__((ext_vector_type(8))) short short8v;
typedef __attribute__((ext_vector_type(4))) float float4v;
typedef unsigned short u16;

__device__ __forceinline__ u16 f2bf(float f) {
    union { float f; unsigned int u; } c; c.f = f;
    unsigned int u = c.u + 0x7FFFu + ((c.u >> 16) & 1u);
    return (u16)(u >> 16);
}

__device__ __forceinline__ short8v cvt8(float4 a, float4 b) {
    short8v t;
    t[0]=(short)f2bf(a.x); t[1]=(short)f2bf(a.y); t[2]=(short)f2bf(a.z); t[3]=(short)f2bf(a.w);
    t[4]=(short)f2bf(b.x); t[5]=(short)f2bf(b.y); t[6]=(short)f2bf(b.z); t[7]=(short)f2bf(b.w);
    return t;
}

__device__ __forceinline__ unsigned int pk2bf(float a, float b) {
    unsigned int r;
    asm("v_cvt_pk_bf16_f32 %0, %1, %2" : "=v"(r) : "v"(a), "v"(b));
    return r;
}

__device__ __forceinline__ float exp2_fast(float x) {
    float r;
    asm("v_exp_f32 %0, %1" : "=v"(r) : "v"(x));
    return r;
}

__device__ __forceinline__ void gload_lds16(const void* g, void* l) {
    __builtin_amdgcn_global_load_lds(
        (const __attribute__((address_space(1))) unsigned int*)g,
        (__attribute__((address_space(3))) unsigned int*)l, 16, 0, 0);
}

// ---------------------------------------------------------------------------
// Convert hidden + 4 weights to bf16 (Wq scaled by 0.125*log2e).
// ---------------------------------------------------------------------------
__global__ __launch_bounds__(256) void convert_inputs(
    const float* __restrict__ hidden, const float* __restrict__ Wq,
    const float* __restrict__ Wk, const float* __restrict__ Wv,
    const float* __restrict__ Wo, u16* __restrict__ hbf, u16* __restrict__ w4)
{
    const int y = blockIdx.y;
    const float* src; u16* dst; int n; float scale = 1.f;
    if (y == 0) { src = hidden; dst = hbf; n = 4096*HID; }
    else {
        src = (y==1) ? Wq : (y==2) ? Wk : (y==3) ? Wv : Wo;
        dst = w4 + (size_t)(y-1)*HID*HID;
        n = HID*HID;
        if (y == 1) scale = QSCALE;
    }
    const int idx = (blockIdx.x*256 + threadIdx.x) * 8;
    if (idx >= n) return;
    float4 f0 = *(const float4*)(src + idx);
    float4 f1 = *(const float4*)(src + idx + 4);
    f0.x*=scale; f0.y*=scale; f0.z*=scale; f0.w*=scale;
    f1.x*=scale; f1.y*=scale; f1.z*=scale; f1.w*=scale;
    *(short8v*)(dst + idx) = cvt8(f0, f1);
}

// ---------------------------------------------------------------------------
// bf16 MFMA GEMM (m97 structure). C[m][n] = sum_k A[m][k]*W[n][k] + bias[n].
// mode 0: z in {0,1,2}. z=0,1 (Q,K): out bf16 (B,nh,S,hd) at obf + z*NTOK.
//         z=2 (V): out bf16 TRANSPOSED (B,nh,hd,S) at ovt (kills transpose kernel).
// mode 1: Wo; out f32 flat (B,S,H).
// ---------------------------------------------------------------------------
__global__ __launch_bounds__(256) void gemm_mfma(
    const u16* __restrict__ A, const u16* __restrict__ W4,
    const float* __restrict__ bA, const float* __restrict__ bB,
    const float* __restrict__ bC, u16* __restrict__ obf,
    u16* __restrict__ ovt, float* __restrict__ of32, int mode)
{
    __shared__ __align__(16) u16 As[128*32];
    __shared__ __align__(16) u16 Bs[128*32];

    const int tid = threadIdx.x;
    const int w = tid >> 6, l = tid & 63;
    const int lx = l & 15, lg = l >> 4;
    const int wr = w >> 1, wc = w & 1;
    const int m0 = blockIdx.x * 128, n0 = blockIdx.y * 128;
    const int z = (mode == 0) ? blockIdx.z : 3;
    const float* bias = (mode == 1) ? bA : (z == 0 ? bA : (z == 1 ? bB : bC));
    const float bscale = (mode == 0 && z == 0) ? QSCALE : 1.0f;
    const u16* Wp = W4 + (size_t)z * (HID*HID);

    float4v acc[4][4];
    const float4v fz = {0.f,0.f,0.f,0.f};
    #pragma unroll
    for (int i = 0; i < 4; i++)
        #pragma unroll
        for (int j = 0; j < 4; j++) acc[i][j] = fz;

    for (int kt = 0; kt < HID/32; kt++) {
        const int k0 = kt * 32;
        __syncthreads();
        #pragma unroll
        for (int rnd = 0; rnd < 2; rnd++) {
            const int ch  = rnd*256 + w*64 + l;
            const int row = ch >> 2, kc = ch & 3;
            gload_lds16(A  + (size_t)(m0+row)*HID + k0 + kc*8,
                        As + (size_t)(rnd*256 + w*64)*8);
            gload_lds16(Wp + (size_t)(n0+row)*HID + k0 + kc*8,
                        Bs + (size_t)(rnd*256 + w*64)*8);
        }
        __syncthreads();
        short8v af[4], bfr[4];
        #pragma unroll
        for (int i = 0; i < 4; i++) {
            af[i]  = *(const short8v*)(As + (wr*64 + i*16 + lx)*32 + lg*8);
            bfr[i] = *(const short8v*)(Bs + (wc*64 + i*16 + lx)*32 + lg*8);
        }
        #pragma unroll
        for (int i = 0; i < 4; i++)
            #pragma unroll
            for (int j = 0; j < 4; j++)
                acc[i][j] = __builtin_amdgcn_mfma_f32_16x16x32_bf16(af[i], bfr[j], acc[i][j], 0, 0, 0);
    }

    #pragma unroll
    for (int j = 0; j < 4; j++) {
        const int col = n0 + wc*64 + j*16 + lx;
        const float bval = bias[col] * bscale;
        const int hh = col >> 6, d = col & 63;
        #pragma unroll
        for (int i = 0; i < 4; i++) {
            const int rbase = m0 + wr*64 + i*16 + lg*4;
            const int bb = rbase >> 11, s = rbase & 2047;
            const float v0 = acc[i][j][0] + bval;
            const float v1 = acc[i][j][1] + bval;
            const float v2 = acc[i][j][2] + bval;
            const float v3 = acc[i][j][3] + bval;
            if (mode == 1) {
                of32[(size_t)(rbase+0)*HID + col] = v0;
                of32[(size_t)(rbase+1)*HID + col] = v1;
                of32[(size_t)(rbase+2)*HID + col] = v2;
                of32[(size_t)(rbase+3)*HID + col] = v3;
            } else if (z == 2) {
                uint2 ow; ow.x = pk2bf(v0, v1); ow.y = pk2bf(v2, v3);
                *(uint2*)&ovt[(((size_t)bb*NH + hh)*HD + d)*S_LEN + s] = ow;
            } else {
                u16* base = obf + (size_t)z * ((size_t)2*S_LEN*HID);
                base[(((size_t)bb*NH + hh)*S_LEN + s+0)*HD + d] = f2bf(v0);
                base[(((size_t)bb*NH + hh)*S_LEN + s+1)*HD + d] = f2bf(v1);
                base[(((size_t)bb*NH + hh)*S_LEN + s+2)*HD + d] = f2bf(v2);
                base[(((size_t)bb*NH + hh)*S_LEN + s+3)*HD + d] = f2bf(v3);
            }
        }
    }
}

// ---------------------------------------------------------------------------
// Flash attention, bf16 MFMA 16x16x32, SWAPPED operands: each lane owns one
// q-row (q = q0 + w*16 + lx) with 16 keys in regs -> in-register softmax.
// Scores are in log2 domain (log2e folded into Wq/bq). Defer-max THR=8.
// Masking via precomputed per-key addends fA/fB + per-tile window class.
// ---------------------------------------------------------------------------
__global__ __launch_bounds__(256) void attn_mfma(
    const u16* __restrict__ Q, const u16* __restrict__ K,
    const u16* __restrict__ Vt, const int* __restrict__ amask,
    const int* __restrict__ gmask, u16* __restrict__ AO)
{
    __shared__ __align__(16) u16 Ks[64*64];   // [key][d] swizzled
    __shared__ __align__(16) u16 Vs[64*64];   // [d][key] swizzled
    __shared__ __align__(16) u16 Ps[4*16*64]; // per-wave [q][key] swizzled (wave-private)
    __shared__ __align__(16) float fA[64];    // am ? 0 : NEG
    __shared__ __align__(16) float fB[64];    // am&&gk ? 0 : NEG

    const int tid = threadIdx.x;
    const int w  = tid >> 6;
    const int l  = tid & 63;
    const int lx = l & 15;
    const int lg = l >> 4;
    const int b  = blockIdx.z;
    const int h  = blockIdx.y;
    const int q0 = blockIdx.x * 64;
    const size_t bh = ((size_t)b*NH + h) * S_LEN;

    const int q_glob = q0 + w*16 + lx;

    short8v aq[2];
    {
        const u16* qp = Q + (bh + q_glob)*HD + lg*8;
        aq[0] = *(const short8v*)(qp);
        aq[1] = *(const short8v*)(qp + 32);
    }
    const int gq = gmask[(size_t)b*S_LEN + q_glob];
    const float* fP = gq ? fA : fB;   // per-lane pointer, hoisted out of k-loop

    float m_i = NEGV, l_i = 0.f;
    float4v o_acc[4];
    const float4v fzv = {0.f, 0.f, 0.f, 0.f};
    #pragma unroll
    for (int db = 0; db < 4; db++) o_acc[db] = fzv;

    const int str = tid >> 2;
    const int stc = tid & 3;
    const int rb  = str * 128;
    const int sw  = (str & 7) << 4;
    const u16* Kbase = K + bh * HD;
    const u16* Vbase = Vt + (size_t)(b*NH + h) * HD * S_LEN;
    const int psw = (lx & 7) << 4;

    for (int kt = 0; kt < S_LEN/64; kt++) {
        const int k0 = kt * 64;
        __syncthreads();
        // ---- stage K tile [key][d] swizzled ----
        {
            const u16* kp = Kbase + (size_t)(k0 + str)*HD + stc*16;
            uint4 u0 = *(const uint4*)(kp);
            uint4 u1 = *(const uint4*)(kp + 8);
            *(uint4*)((char*)Ks + rb + ((stc*32)      ^ sw)) = u0;
            *(uint4*)((char*)Ks + rb + ((stc*32 + 16) ^ sw)) = u1;
        }
        // ---- stage Vt tile [d][key] swizzled ----
        {
            const u16* vp = Vbase + (size_t)str*S_LEN + k0 + stc*16;
            uint4 u0 = *(const uint4*)(vp);
            uint4 u1 = *(const uint4*)(vp + 8);
            *(uint4*)((char*)Vs + rb + ((stc*32)      ^ sw)) = u0;
            *(uint4*)((char*)Vs + rb + ((stc*32 + 16) ^ sw)) = u1;
        }
        // ---- per-key mask addends ----
        if (tid < 64) {
            const int am = amask[(size_t)b*S_LEN + k0 + tid];
            const int gk = gmask[(size_t)b*S_LEN + k0 + tid];
            fA[tid] = am ? 0.f : NEGV;
            fB[tid] = (am && gk) ? 0.f : NEGV;
        }
        __syncthreads();

        // ---- QK^T swapped: sacc[kb][r] = S[key=k0+kb*16+lg*4+r][q=q_glob] ----
        float4v sacc[4];
        #pragma unroll
        for (int kb = 0; kb < 4; kb++) sacc[kb] = fzv;
        #pragma unroll
        for (int kb = 0; kb < 4; kb++) {
            const int key = kb*16 + lx;
            const int ksw = (key & 7) << 4;
            #pragma unroll
            for (int ks = 0; ks < 2; ks++) {
                short8v bk = *(const short8v*)((char*)Ks + key*128 + ((16*lg + 64*ks) ^ ksw));
                sacc[kb] = __builtin_amdgcn_mfma_f32_16x16x32_bf16(bk, aq[ks], sacc[kb], 0, 0, 0);
            }
        }

        // ---- masking: tile-uniform window class ----
        float sv[4][4];
        const int adq = (k0 > q0) ? (k0 - q0) : (q0 - k0);
        if (adq <= 64) {
            // every (q,k) pair in window: ok = am
            #pragma unroll
            for (int kb = 0; kb < 4; kb++) {
                float4 fa4 = *(const float4*)&fA[kb*16 + lg*4];
                sv[kb][0] = sacc[kb][0] + fa4.x;
                sv[kb][1] = sacc[kb][1] + fa4.y;
                sv[kb][2] = sacc[kb][2] + fa4.z;
                sv[kb][3] = sacc[kb][3] + fa4.w;
            }
        } else if (adq >= 192) {
            // no pair in window: ok = am && (gq || gk)
            #pragma unroll
            for (int kb = 0; kb < 4; kb++) {
                float4 fp4 = *(const float4*)&fP[kb*16 + lg*4];
                sv[kb][0] = sacc[kb][0] + fp4.x;
                sv[kb][1] = sacc[kb][1] + fp4.y;
                sv[kb][2] = sacc[kb][2] + fp4.z;
                sv[kb][3] = sacc[kb][3] + fp4.w;
            }
        } else {
            // mixed (2 of 32 tiles)
            #pragma unroll
            for (int kb = 0; kb < 4; kb++) {
                float4 fa4 = *(const float4*)&fA[kb*16 + lg*4];
                float4 fb4 = *(const float4*)&fB[kb*16 + lg*4];
                const int e = q_glob - (k0 + kb*16 + lg*4);
                #pragma unroll
                for (int r = 0; r < 4; r++) {
                    int dd = e - r; dd = dd < 0 ? -dd : dd;
                    const bool wing = (dd <= WIN) || gq;
                    const float fa = (&fa4.x)[r], fb = (&fb4.x)[r];
                    sv[kb][r] = sacc[kb][r] + (wing ? fa : fb);
                }
            }
        }

        // ---- in-register online softmax (one q-row per lane) ----
        float mloc;
        {
            float t0 = fmaxf(fmaxf(sv[0][0], sv[0][1]), fmaxf(sv[0][2], sv[0][3]));
            float t1 = fmaxf(fmaxf(sv[1][0], sv[1][1]), fmaxf(sv[1][2], sv[1][3]));
            float t2 = fmaxf(fmaxf(sv[2][0], sv[2][1]), fmaxf(sv[2][2], sv[2][3]));
            float t3 = fmaxf(fmaxf(sv[3][0], sv[3][1]), fmaxf(sv[3][2], sv[3][3]));
            mloc = fmaxf(fmaxf(t0, t1), fmaxf(t2, t3));
        }
        mloc = fmaxf(mloc, __shfl_xor(mloc, 16));
        mloc = fmaxf(mloc, __shfl_xor(mloc, 32));
        if (__any(mloc > m_i + 8.0f)) {          // defer-max (T13)
            const float mnew = fmaxf(m_i, mloc);
            const float sc = exp2_fast(m_i - mnew);
            l_i *= sc;
            #pragma unroll
            for (int db = 0; db < 4; db++)
                #pragma unroll
                for (int r = 0; r < 4; r++) o_acc[db][r] *= sc;
            m_i = mnew;
        }
        float p[4][4];
        float lsum = 0.f;
        #pragma unroll
        for (int kb = 0; kb < 4; kb++)
            #pragma unroll
            for (int r = 0; r < 4; r++) {
                p[kb][r] = exp2_fast(sv[kb][r] - m_i);
                lsum += p[kb][r];
            }
        lsum += __shfl_xor(lsum, 16);
        lsum += __shfl_xor(lsum, 32);
        l_i += lsum;

        // ---- write P^T row (wave-private Ps, no barrier needed) ----
        #pragma unroll
        for (int kb = 0; kb < 4; kb++) {
            uint2 pw;
            pw.x = pk2bf(p[kb][0], p[kb][1]);
            pw.y = pk2bf(p[kb][2], p[kb][3]);
            *(uint2*)((char*)Ps + w*2048 + lx*128 + ((kb*32 + lg*8) ^ psw)) = pw;
        }

        // ---- PV swapped: o_acc[db] = O^T[d-block][q] ----
        #pragma unroll
        for (int ks = 0; ks < 2; ks++) {
            short8v pa = *(const short8v*)((char*)Ps + w*2048 + lx*128 +
                                           ((16*lg + 64*ks) ^ psw));
            #pragma unroll
            for (int db = 0; db < 4; db++) {
                const int drow = db*16 + lx;
                short8v bv = *(const short8v*)((char*)Vs + drow*128 +
                                               ((16*lg + 64*ks) ^ ((drow & 7) << 4)));
                o_acc[db] = __builtin_amdgcn_mfma_f32_16x16x32_bf16(bv, pa, o_acc[db], 0, 0, 0);
            }
        }
    }

    // ---- epilogue: o_acc[db][r] = O[q_glob][d=db*16+lg*4+r], packed stores ----
    {
        const float inv = 1.f / l_i;
        u16* op = AO + ((size_t)b*S_LEN + q_glob)*HID + h*HD + lg*4;
        #pragma unroll
        for (int db = 0; db < 4; db++) {
            uint2 ow;
            ow.x = pk2bf(o_acc[db][0]*inv, o_acc[db][1]*inv);
            ow.y = pk2bf(o_acc[db][2]*inv, o_acc[db][3]*inv);
            *(uint2*)(op + db*16) = ow;
        }
    }
}

// ---------------------------------------------------------------------------
extern "C" void kernel_launch(void* const* d_in, const int* in_sizes, int n_in,
                              void* d_out, int out_size, void* d_ws, size_t ws_size,
                              hipStream_t stream)
{
    const float* hidden = (const float*)d_in[0];
    const int*   amask  = (const int*)d_in[1];
    const int*   gmask  = (const int*)d_in[2];
    const float* Wq = (const float*)d_in[3];
    const float* bq = (const float*)d_in[4];
    const float* Wk = (const float*)d_in[5];
    const float* bk = (const float*)d_in[6];
    const float* Wv = (const float*)d_in[7];
    const float* bv = (const float*)d_in[8];
    const float* Wo = (const float*)d_in[9];
    const float* bo = (const float*)d_in[10];
    float* out = (float*)d_out;

    char* ws = (char*)d_ws;
    const size_t NTOK = (size_t)2 * S_LEN * HID;   // 3,145,728
    u16* hbf   = (u16*)(ws);
    u16* w4    = (u16*)(ws + 6291456);
    u16* qkvbf = (u16*)(ws + 11010048);            // Q, K (2 x NTOK)
    u16* vtbf  = (u16*)(ws + 29884416);            // V transposed (B,nh,hd,S)
    u16* aobf  = (u16*)(ws + 36175872);

    convert_inputs<<<dim3(1536, 5), 256, 0, stream>>>(hidden, Wq, Wk, Wv, Wo, hbf, w4);

    // Q,K,V projections; V written pre-transposed (z=2) -> no transpose kernel
    gemm_mfma<<<dim3(32, 6, 3), 256, 0, stream>>>(hbf, w4, bq, bk, bv, qkvbf, vtbf, nullptr, 0);

    u16* Qbf = qkvbf;
    u16* Kbf = qkvbf + NTOK;

    attn_mfma<<<dim3(S_LEN/64, NH, 2), 256, 0, stream>>>(Qbf, Kbf, vtbf, amask, gmask, aobf);

    gemm_mfma<<<dim3(32, 6), 256, 0, stream>>>(aobf, w4, bo, nullptr, nullptr, nullptr, nullptr, out, 1);
}

// Round 6
// 107.947 us; speedup vs baseline: 19.1557x; 1.0421x over previous
//
#include <hip/hip_runtime.h>
#include <math.h>

#define S_LEN 2048
#define HID   768
#define NH    12
#define HD    64
#define WIN   128
#define NEGV  (-1e30f)
#define QSCALE 0.1803368801111204f   /* 0.125 * log2(e): scores in log2 domain */

typedef __attribute__((ext_vector_type(8))) short short8v;
typedef __attribute__((ext_vector_type(4))) float float4v;
typedef unsigned short u16;

__device__ __forceinline__ u16 f2bf(float f) {
    union { float f; unsigned int u; } c; c.f = f;
    unsigned int u = c.u + 0x7FFFu + ((c.u >> 16) & 1u);
    return (u16)(u >> 16);
}

__device__ __forceinline__ short8v cvt8(float4 a, float4 b) {
    short8v t;
    t[0]=(short)f2bf(a.x); t[1]=(short)f2bf(a.y); t[2]=(short)f2bf(a.z); t[3]=(short)f2bf(a.w);
    t[4]=(short)f2bf(b.x); t[5]=(short)f2bf(b.y); t[6]=(short)f2bf(b.z); t[7]=(short)f2bf(b.w);
    return t;
}

__device__ __forceinline__ unsigned int pk2bf(float a, float b) {
    unsigned int r;
    asm("v_cvt_pk_bf16_f32 %0, %1, %2" : "=v"(r) : "v"(a), "v"(b));
    return r;
}

__device__ __forceinline__ float exp2_fast(float x) {
    float r;
    asm("v_exp_f32 %0, %1" : "=v"(r) : "v"(x));
    return r;
}

__device__ __forceinline__ void gload_lds16(const void* g, void* l) {
    __builtin_amdgcn_global_load_lds(
        (const __attribute__((address_space(1))) unsigned int*)g,
        (__attribute__((address_space(3))) unsigned int*)l, 16, 0, 0);
}

// ---------------------------------------------------------------------------
// Convert hidden + 4 weights to bf16 (Wq scaled by 0.125*log2e).
// ---------------------------------------------------------------------------
__global__ __launch_bounds__(256) void convert_inputs(
    const float* __restrict__ hidden, const float* __restrict__ Wq,
    const float* __restrict__ Wk, const float* __restrict__ Wv,
    const float* __restrict__ Wo, u16* __restrict__ hbf, u16* __restrict__ w4)
{
    const int y = blockIdx.y;
    const float* src; u16* dst; int n; float scale = 1.f;
    if (y == 0) { src = hidden; dst = hbf; n = 4096*HID; }
    else {
        src = (y==1) ? Wq : (y==2) ? Wk : (y==3) ? Wv : Wo;
        dst = w4 + (size_t)(y-1)*HID*HID;
        n = HID*HID;
        if (y == 1) scale = QSCALE;
    }
    const int idx = (blockIdx.x*256 + threadIdx.x) * 8;
    if (idx >= n) return;
    float4 f0 = *(const float4*)(src + idx);
    float4 f1 = *(const float4*)(src + idx + 4);
    f0.x*=scale; f0.y*=scale; f0.z*=scale; f0.w*=scale;
    f1.x*=scale; f1.y*=scale; f1.z*=scale; f1.w*=scale;
    *(short8v*)(dst + idx) = cvt8(f0, f1);
}

// ---------------------------------------------------------------------------
// bf16 MFMA GEMM (m97 structure). C[m][n] = sum_k A[m][k]*W[n][k] + bias[n].
// mode 0: z in {0,1,2}. z=0,1 (Q,K): out bf16 (B,nh,S,hd) at obf + z*NTOK.
//         z=2 (V): out bf16 TRANSPOSED (B,nh,hd,S) at ovt.
// mode 1: Wo; out f32 flat (B,S,H).
// ---------------------------------------------------------------------------
__global__ __launch_bounds__(256) void gemm_mfma(
    const u16* __restrict__ A, const u16* __restrict__ W4,
    const float* __restrict__ bA, const float* __restrict__ bB,
    const float* __restrict__ bC, u16* __restrict__ obf,
    u16* __restrict__ ovt, float* __restrict__ of32, int mode)
{
    __shared__ __align__(16) u16 As[128*32];
    __shared__ __align__(16) u16 Bs[128*32];

    const int tid = threadIdx.x;
    const int w = tid >> 6, l = tid & 63;
    const int lx = l & 15, lg = l >> 4;
    const int wr = w >> 1, wc = w & 1;
    const int m0 = blockIdx.x * 128, n0 = blockIdx.y * 128;
    const int z = (mode == 0) ? blockIdx.z : 3;
    const float* bias = (mode == 1) ? bA : (z == 0 ? bA : (z == 1 ? bB : bC));
    const float bscale = (mode == 0 && z == 0) ? QSCALE : 1.0f;
    const u16* Wp = W4 + (size_t)z * (HID*HID);

    float4v acc[4][4];
    const float4v fz = {0.f,0.f,0.f,0.f};
    #pragma unroll
    for (int i = 0; i < 4; i++)
        #pragma unroll
        for (int j = 0; j < 4; j++) acc[i][j] = fz;

    for (int kt = 0; kt < HID/32; kt++) {
        const int k0 = kt * 32;
        __syncthreads();
        #pragma unroll
        for (int rnd = 0; rnd < 2; rnd++) {
            const int ch  = rnd*256 + w*64 + l;
            const int row = ch >> 2, kc = ch & 3;
            gload_lds16(A  + (size_t)(m0+row)*HID + k0 + kc*8,
                        As + (size_t)(rnd*256 + w*64)*8);
            gload_lds16(Wp + (size_t)(n0+row)*HID + k0 + kc*8,
                        Bs + (size_t)(rnd*256 + w*64)*8);
        }
        __syncthreads();
        short8v af[4], bfr[4];
        #pragma unroll
        for (int i = 0; i < 4; i++) {
            af[i]  = *(const short8v*)(As + (wr*64 + i*16 + lx)*32 + lg*8);
            bfr[i] = *(const short8v*)(Bs + (wc*64 + i*16 + lx)*32 + lg*8);
        }
        #pragma unroll
        for (int i = 0; i < 4; i++)
            #pragma unroll
            for (int j = 0; j < 4; j++)
                acc[i][j] = __builtin_amdgcn_mfma_f32_16x16x32_bf16(af[i], bfr[j], acc[i][j], 0, 0, 0);
    }

    #pragma unroll
    for (int j = 0; j < 4; j++) {
        const int col = n0 + wc*64 + j*16 + lx;
        const float bval = bias[col] * bscale;
        const int hh = col >> 6, d = col & 63;
        #pragma unroll
        for (int i = 0; i < 4; i++) {
            const int rbase = m0 + wr*64 + i*16 + lg*4;
            const int bb = rbase >> 11, s = rbase & 2047;
            const float v0 = acc[i][j][0] + bval;
            const float v1 = acc[i][j][1] + bval;
            const float v2 = acc[i][j][2] + bval;
            const float v3 = acc[i][j][3] + bval;
            if (mode == 1) {
                of32[(size_t)(rbase+0)*HID + col] = v0;
                of32[(size_t)(rbase+1)*HID + col] = v1;
                of32[(size_t)(rbase+2)*HID + col] = v2;
                of32[(size_t)(rbase+3)*HID + col] = v3;
            } else if (z == 2) {
                uint2 ow; ow.x = pk2bf(v0, v1); ow.y = pk2bf(v2, v3);
                *(uint2*)&ovt[(((size_t)bb*NH + hh)*HD + d)*S_LEN + s] = ow;
            } else {
                u16* base = obf + (size_t)z * ((size_t)2*S_LEN*HID);
                base[(((size_t)bb*NH + hh)*S_LEN + s+0)*HD + d] = f2bf(v0);
                base[(((size_t)bb*NH + hh)*S_LEN + s+1)*HD + d] = f2bf(v1);
                base[(((size_t)bb*NH + hh)*S_LEN + s+2)*HD + d] = f2bf(v2);
                base[(((size_t)bb*NH + hh)*S_LEN + s+3)*HD + d] = f2bf(v3);
            }
        }
    }
}

// ---------------------------------------------------------------------------
// Flash attention, swapped-operand bf16 MFMA, in-register softmax (log2 dom),
// defer-max THR=8, tile-class masking.
// Round 6: T14 async-stage (global->regs early, LDS-write late) + K/V LDS
// double-buffer (unrolled x2, named buffers) + T1 XCD swizzle (768 = 8*96).
// ---------------------------------------------------------------------------
__global__ __launch_bounds__(256) void attn_mfma(
    const u16* __restrict__ Q, const u16* __restrict__ K,
    const u16* __restrict__ Vt, const int* __restrict__ amask,
    const int* __restrict__ gmask, u16* __restrict__ AO)
{
    __shared__ __align__(16) u16 KsA[64*64], VsA[64*64];
    __shared__ __align__(16) u16 KsB[64*64], VsB[64*64];
    __shared__ __align__(16) u16 Ps[4*16*64];
    __shared__ __align__(16) float fA[64];    // am ? 0 : NEG
    __shared__ __align__(16) float fB[64];    // am&&gk ? 0 : NEG

    const int tid = threadIdx.x;
    const int w  = tid >> 6;
    const int l  = tid & 63;
    const int lx = l & 15;
    const int lg = l >> 4;

    // XCD-aware swizzle: 768 blocks = 8 XCDs x 96; each XCD gets 3 (b,h) groups
    const int bid = blockIdx.x;
    const int swz = (bid & 7) * 96 + (bid >> 3);
    const int q0 = (swz & 31) * 64;
    const int hb = swz >> 5;
    const int h  = hb % NH;
    const int b  = hb / NH;
    const size_t bh = ((size_t)b*NH + h) * S_LEN;

    const int q_glob = q0 + w*16 + lx;

    short8v aq[2];
    {
        const u16* qp = Q + (bh + q_glob)*HD + lg*8;
        aq[0] = *(const short8v*)(qp);
        aq[1] = *(const short8v*)(qp + 32);
    }
    const int gq = gmask[(size_t)b*S_LEN + q_glob];
    const float* fP = gq ? fA : fB;

    float m_i = NEGV, l_i = 0.f;
    float4v o_acc[4];
    const float4v fzv = {0.f, 0.f, 0.f, 0.f};
    #pragma unroll
    for (int db = 0; db < 4; db++) o_acc[db] = fzv;

    const int str = tid >> 2;
    const int stc = tid & 3;
    const int rb  = str * 128;
    const int sw  = (str & 7) << 4;
    const u16* Kbase = K + bh * HD;
    const u16* Vbase = Vt + (size_t)(b*NH + h) * HD * S_LEN;
    const int psw = (lx & 7) << 4;

    uint4 rk0, rk1, rv0, rv1;
    int ram = 0, rgk = 0;

#define STAGE_REGS(KT) do {                                                   \
    const int kk0_ = (KT) * 64;                                               \
    const u16* kp_ = Kbase + (size_t)(kk0_ + str)*HD + stc*16;                \
    rk0 = *(const uint4*)(kp_); rk1 = *(const uint4*)(kp_ + 8);               \
    const u16* vp_ = Vbase + (size_t)str*S_LEN + kk0_ + stc*16;               \
    rv0 = *(const uint4*)(vp_); rv1 = *(const uint4*)(vp_ + 8);               \
    if (tid < 64) {                                                           \
        ram = amask[(size_t)b*S_LEN + kk0_ + tid];                            \
        rgk = gmask[(size_t)b*S_LEN + kk0_ + tid];                            \
    }                                                                         \
} while(0)

#define WRITE_LDS(KS, VS) do {                                                \
    *(uint4*)((char*)(KS) + rb + ((stc*32)      ^ sw)) = rk0;                 \
    *(uint4*)((char*)(KS) + rb + ((stc*32 + 16) ^ sw)) = rk1;                 \
    *(uint4*)((char*)(VS) + rb + ((stc*32)      ^ sw)) = rv0;                 \
    *(uint4*)((char*)(VS) + rb + ((stc*32 + 16) ^ sw)) = rv1;                 \
    if (tid < 64) {                                                           \
        fA[tid] = ram ? 0.f : NEGV;                                           \
        fB[tid] = (ram && rgk) ? 0.f : NEGV;                                  \
    }                                                                         \
} while(0)

#define COMPUTE(KS, VS, K0) do {                                              \
    float4v sacc[4];                                                          \
    _Pragma("unroll")                                                         \
    for (int kb = 0; kb < 4; kb++) sacc[kb] = fzv;                            \
    _Pragma("unroll")                                                         \
    for (int kb = 0; kb < 4; kb++) {                                          \
        const int key_ = kb*16 + lx;                                          \
        const int ksw_ = (key_ & 7) << 4;                                     \
        _Pragma("unroll")                                                     \
        for (int ks = 0; ks < 2; ks++) {                                      \
            short8v bk_ = *(const short8v*)((char*)(KS) + key_*128 +          \
                                            ((16*lg + 64*ks) ^ ksw_));        \
            sacc[kb] = __builtin_amdgcn_mfma_f32_16x16x32_bf16(bk_, aq[ks],   \
                                                          sacc[kb], 0, 0, 0); \
        }                                                                     \
    }                                                                         \
    float sv[4][4];                                                           \
    const int adq_ = ((K0) > q0) ? ((K0) - q0) : (q0 - (K0));                 \
    if (adq_ <= 64) {                                                         \
        _Pragma("unroll")                                                     \
        for (int kb = 0; kb < 4; kb++) {                                      \
            float4 fa4 = *(const float4*)&fA[kb*16 + lg*4];                   \
            sv[kb][0] = sacc[kb][0] + fa4.x;                                  \
            sv[kb][1] = sacc[kb][1] + fa4.y;                                  \
            sv[kb][2] = sacc[kb][2] + fa4.z;                                  \
            sv[kb][3] = sacc[kb][3] + fa4.w;                                  \
        }                                                                     \
    } else if (adq_ >= 192) {                                                 \
        _Pragma("unroll")                                                     \
        for (int kb = 0; kb < 4; kb++) {                                      \
            float4 fp4 = *(const float4*)&fP[kb*16 + lg*4];                   \
            sv[kb][0] = sacc[kb][0] + fp4.x;                                  \
            sv[kb][1] = sacc[kb][1] + fp4.y;                                  \
            sv[kb][2] = sacc[kb][2] + fp4.z;                                  \
            sv[kb][3] = sacc[kb][3] + fp4.w;                                  \
        }                                                                     \
    } else {                                                                  \
        _Pragma("unroll")                                                     \
        for (int kb = 0; kb < 4; kb++) {                                      \
            float4 fa4 = *(const float4*)&fA[kb*16 + lg*4];                   \
            float4 fb4 = *(const float4*)&fB[kb*16 + lg*4];                   \
            const int e_ = q_glob - ((K0) + kb*16 + lg*4);                    \
            _Pragma("unroll")                                                 \
            for (int r = 0; r < 4; r++) {                                     \
                int dd_ = e_ - r; dd_ = dd_ < 0 ? -dd_ : dd_;                 \
                const bool wing_ = (dd_ <= WIN) || gq;                        \
                const float fa_ = (&fa4.x)[r], fb_ = (&fb4.x)[r];             \
                sv[kb][r] = sacc[kb][r] + (wing_ ? fa_ : fb_);                \
            }                                                                 \
        }                                                                     \
    }                                                                         \
    float mloc;                                                               \
    {                                                                         \
        float t0 = fmaxf(fmaxf(sv[0][0], sv[0][1]), fmaxf(sv[0][2], sv[0][3]));\
        float t1 = fmaxf(fmaxf(sv[1][0], sv[1][1]), fmaxf(sv[1][2], sv[1][3]));\
        float t2 = fmaxf(fmaxf(sv[2][0], sv[2][1]), fmaxf(sv[2][2], sv[2][3]));\
        float t3 = fmaxf(fmaxf(sv[3][0], sv[3][1]), fmaxf(sv[3][2], sv[3][3]));\
        mloc = fmaxf(fmaxf(t0, t1), fmaxf(t2, t3));                           \
    }                                                                         \
    mloc = fmaxf(mloc, __shfl_xor(mloc, 16));                                 \
    mloc = fmaxf(mloc, __shfl_xor(mloc, 32));                                 \
    if (__any(mloc > m_i + 8.0f)) {                                           \
        const float mnew_ = fmaxf(m_i, mloc);                                 \
        const float sc_ = exp2_fast(m_i - mnew_);                             \
        l_i *= sc_;                                                           \
        _Pragma("unroll")                                                     \
        for (int db = 0; db < 4; db++)                                        \
            _Pragma("unroll")                                                 \
            for (int r = 0; r < 4; r++) o_acc[db][r] *= sc_;                  \
        m_i = mnew_;                                                          \
    }                                                                         \
    float p[4][4];                                                            \
    float lsum = 0.f;                                                         \
    _Pragma("unroll")                                                         \
    for (int kb = 0; kb < 4; kb++)                                            \
        _Pragma("unroll")                                                     \
        for (int r = 0; r < 4; r++) {                                         \
            p[kb][r] = exp2_fast(sv[kb][r] - m_i);                            \
            lsum += p[kb][r];                                                 \
        }                                                                     \
    lsum += __shfl_xor(lsum, 16);                                             \
    lsum += __shfl_xor(lsum, 32);                                             \
    l_i += lsum;                                                              \
    _Pragma("unroll")                                                         \
    for (int kb = 0; kb < 4; kb++) {                                          \
        uint2 pw;                                                             \
        pw.x = pk2bf(p[kb][0], p[kb][1]);                                     \
        pw.y = pk2bf(p[kb][2], p[kb][3]);                                     \
        *(uint2*)((char*)Ps + w*2048 + lx*128 + ((kb*32 + lg*8) ^ psw)) = pw; \
    }                                                                         \
    _Pragma("unroll")                                                         \
    for (int ks = 0; ks < 2; ks++) {                                          \
        short8v pa_ = *(const short8v*)((char*)Ps + w*2048 + lx*128 +         \
                                        ((16*lg + 64*ks) ^ psw));             \
        _Pragma("unroll")                                                     \
        for (int db = 0; db < 4; db++) {                                      \
            const int drow_ = db*16 + lx;                                     \
            short8v bv_ = *(const short8v*)((char*)(VS) + drow_*128 +         \
                                    ((16*lg + 64*ks) ^ ((drow_ & 7) << 4)));  \
            o_acc[db] = __builtin_amdgcn_mfma_f32_16x16x32_bf16(bv_, pa_,     \
                                                          o_acc[db], 0, 0, 0);\
        }                                                                     \
    }                                                                         \
} while(0)

    // prologue: stage tile 0 into buffer A
    STAGE_REGS(0);
    WRITE_LDS(KsA, VsA);
    __syncthreads();

    for (int kt = 0; kt < S_LEN/64; kt += 2) {
        STAGE_REGS(kt+1);                 // issue loads for tile kt+1 early
        COMPUTE(KsA, VsA, kt*64);         // compute tile kt from buffer A
        __syncthreads();
        WRITE_LDS(KsB, VsB);              // write tile kt+1 to buffer B
        __syncthreads();
        {
            const int kn = (kt+2 < S_LEN/64) ? (kt+2) : (S_LEN/64 - 1);
            STAGE_REGS(kn);               // issue loads for tile kt+2 early
        }
        COMPUTE(KsB, VsB, (kt+1)*64);     // compute tile kt+1 from buffer B
        __syncthreads();
        WRITE_LDS(KsA, VsA);              // write tile kt+2 to buffer A
        __syncthreads();
    }

#undef STAGE_REGS
#undef WRITE_LDS
#undef COMPUTE

    // epilogue: o_acc[db][r] = O[q_glob][d=db*16+lg*4+r], packed stores
    {
        const float inv = 1.f / l_i;
        u16* op = AO + ((size_t)b*S_LEN + q_glob)*HID + h*HD + lg*4;
        #pragma unroll
        for (int db = 0; db < 4; db++) {
            uint2 ow;
            ow.x = pk2bf(o_acc[db][0]*inv, o_acc[db][1]*inv);
            ow.y = pk2bf(o_acc[db][2]*inv, o_acc[db][3]*inv);
            *(uint2*)(op + db*16) = ow;
        }
    }
}

// ---------------------------------------------------------------------------
extern "C" void kernel_launch(void* const* d_in, const int* in_sizes, int n_in,
                              void* d_out, int out_size, void* d_ws, size_t ws_size,
                              hipStream_t stream)
{
    const float* hidden = (const float*)d_in[0];
    const int*   amask  = (const int*)d_in[1];
    const int*   gmask  = (const int*)d_in[2];
    const float* Wq = (const float*)d_in[3];
    const float* bq = (const float*)d_in[4];
    const float* Wk = (const float*)d_in[5];
    const float* bk = (const float*)d_in[6];
    const float* Wv = (const float*)d_in[7];
    const float* bv = (const float*)d_in[8];
    const float* Wo = (const float*)d_in[9];
    const float* bo = (const float*)d_in[10];
    float* out = (float*)d_out;

    char* ws = (char*)d_ws;
    const size_t NTOK = (size_t)2 * S_LEN * HID;   // 3,145,728
    u16* hbf   = (u16*)(ws);
    u16* w4    = (u16*)(ws + 6291456);
    u16* qkvbf = (u16*)(ws + 11010048);            // Q, K (2 x NTOK)
    u16* vtbf  = (u16*)(ws + 29884416);            // V transposed (B,nh,hd,S)
    u16* aobf  = (u16*)(ws + 36175872);

    convert_inputs<<<dim3(1536, 5), 256, 0, stream>>>(hidden, Wq, Wk, Wv, Wo, hbf, w4);

    gemm_mfma<<<dim3(32, 6, 3), 256, 0, stream>>>(hbf, w4, bq, bk, bv, qkvbf, vtbf, nullptr, 0);

    u16* Qbf = qkvbf;
    u16* Kbf = qkvbf + NTOK;

    attn_mfma<<<dim3(768), 256, 0, stream>>>(Qbf, Kbf, vtbf, amask, gmask, aobf);

    gemm_mfma<<<dim3(32, 6), 256, 0, stream>>>(aobf, w4, bo, nullptr, nullptr, nullptr, nullptr, out, 1);
}

// Round 7
// 106.089 us; speedup vs baseline: 19.4911x; 1.0175x over previous
//
#include <hip/hip_runtime.h>
#include <math.h>

#define S_LEN 2048
#define HID   768
#define NH    12
#define HD    64
#define WIN   128
#define NEGV  (-1e30f)
#define QSCALE 0.1803368801111204f   /* 0.125 * log2(e): scores in log2 domain */

typedef __attribute__((ext_vector_type(8))) short short8v;
typedef __attribute__((ext_vector_type(4))) float float4v;
typedef unsigned short u16;

__device__ __forceinline__ u16 f2bf(float f) {
    union { float f; unsigned int u; } c; c.f = f;
    unsigned int u = c.u + 0x7FFFu + ((c.u >> 16) & 1u);
    return (u16)(u >> 16);
}

__device__ __forceinline__ short8v cvt8(float4 a, float4 b) {
    short8v t;
    t[0]=(short)f2bf(a.x); t[1]=(short)f2bf(a.y); t[2]=(short)f2bf(a.z); t[3]=(short)f2bf(a.w);
    t[4]=(short)f2bf(b.x); t[5]=(short)f2bf(b.y); t[6]=(short)f2bf(b.z); t[7]=(short)f2bf(b.w);
    return t;
}

__device__ __forceinline__ unsigned int pk2bf(float a, float b) {
    unsigned int r;
    asm("v_cvt_pk_bf16_f32 %0, %1, %2" : "=v"(r) : "v"(a), "v"(b));
    return r;
}

__device__ __forceinline__ float exp2_fast(float x) {
    float r;
    asm("v_exp_f32 %0, %1" : "=v"(r) : "v"(x));
    return r;
}

__device__ __forceinline__ void gload_lds16(const void* g, void* l) {
    __builtin_amdgcn_global_load_lds(
        (const __attribute__((address_space(1))) unsigned int*)g,
        (__attribute__((address_space(3))) unsigned int*)l, 16, 0, 0);
}

// ---------------------------------------------------------------------------
// Convert hidden + 4 weights to bf16 (Wq scaled by 0.125*log2e).
// ---------------------------------------------------------------------------
__global__ __launch_bounds__(256) void convert_inputs(
    const float* __restrict__ hidden, const float* __restrict__ Wq,
    const float* __restrict__ Wk, const float* __restrict__ Wv,
    const float* __restrict__ Wo, u16* __restrict__ hbf, u16* __restrict__ w4)
{
    const int y = blockIdx.y;
    const float* src; u16* dst; int n; float scale = 1.f;
    if (y == 0) { src = hidden; dst = hbf; n = 4096*HID; }
    else {
        src = (y==1) ? Wq : (y==2) ? Wk : (y==3) ? Wv : Wo;
        dst = w4 + (size_t)(y-1)*HID*HID;
        n = HID*HID;
        if (y == 1) scale = QSCALE;
    }
    const int idx = (blockIdx.x*256 + threadIdx.x) * 8;
    if (idx >= n) return;
    float4 f0 = *(const float4*)(src + idx);
    float4 f1 = *(const float4*)(src + idx + 4);
    f0.x*=scale; f0.y*=scale; f0.z*=scale; f0.w*=scale;
    f1.x*=scale; f1.y*=scale; f1.z*=scale; f1.w*=scale;
    *(short8v*)(dst + idx) = cvt8(f0, f1);
}

// ---------------------------------------------------------------------------
// bf16 MFMA GEMM (m97 structure). C[m][n] = sum_k A[m][k]*W[n][k] + bias[n].
// mode 0: z in {0,1,2}. z=0,1 (Q,K): out bf16 (B,nh,S,hd) at obf + z*NTOK.
//         z=2 (V): out bf16 TRANSPOSED (B,nh,hd,S) at ovt.
// mode 1: Wo; out f32 flat (B,S,H).
// ---------------------------------------------------------------------------
__global__ __launch_bounds__(256) void gemm_mfma(
    const u16* __restrict__ A, const u16* __restrict__ W4,
    const float* __restrict__ bA, const float* __restrict__ bB,
    const float* __restrict__ bC, u16* __restrict__ obf,
    u16* __restrict__ ovt, float* __restrict__ of32, int mode)
{
    __shared__ __align__(16) u16 As[128*32];
    __shared__ __align__(16) u16 Bs[128*32];

    const int tid = threadIdx.x;
    const int w = tid >> 6, l = tid & 63;
    const int lx = l & 15, lg = l >> 4;
    const int wr = w >> 1, wc = w & 1;
    const int m0 = blockIdx.x * 128, n0 = blockIdx.y * 128;
    const int z = (mode == 0) ? blockIdx.z : 3;
    const float* bias = (mode == 1) ? bA : (z == 0 ? bA : (z == 1 ? bB : bC));
    const float bscale = (mode == 0 && z == 0) ? QSCALE : 1.0f;
    const u16* Wp = W4 + (size_t)z * (HID*HID);

    float4v acc[4][4];
    const float4v fz = {0.f,0.f,0.f,0.f};
    #pragma unroll
    for (int i = 0; i < 4; i++)
        #pragma unroll
        for (int j = 0; j < 4; j++) acc[i][j] = fz;

    for (int kt = 0; kt < HID/32; kt++) {
        const int k0 = kt * 32;
        __syncthreads();
        #pragma unroll
        for (int rnd = 0; rnd < 2; rnd++) {
            const int ch  = rnd*256 + w*64 + l;
            const int row = ch >> 2, kc = ch & 3;
            gload_lds16(A  + (size_t)(m0+row)*HID + k0 + kc*8,
                        As + (size_t)(rnd*256 + w*64)*8);
            gload_lds16(Wp + (size_t)(n0+row)*HID + k0 + kc*8,
                        Bs + (size_t)(rnd*256 + w*64)*8);
        }
        __syncthreads();
        short8v af[4], bfr[4];
        #pragma unroll
        for (int i = 0; i < 4; i++) {
            af[i]  = *(const short8v*)(As + (wr*64 + i*16 + lx)*32 + lg*8);
            bfr[i] = *(const short8v*)(Bs + (wc*64 + i*16 + lx)*32 + lg*8);
        }
        #pragma unroll
        for (int i = 0; i < 4; i++)
            #pragma unroll
            for (int j = 0; j < 4; j++)
                acc[i][j] = __builtin_amdgcn_mfma_f32_16x16x32_bf16(af[i], bfr[j], acc[i][j], 0, 0, 0);
    }

    #pragma unroll
    for (int j = 0; j < 4; j++) {
        const int col = n0 + wc*64 + j*16 + lx;
        const float bval = bias[col] * bscale;
        const int hh = col >> 6, d = col & 63;
        #pragma unroll
        for (int i = 0; i < 4; i++) {
            const int rbase = m0 + wr*64 + i*16 + lg*4;
            const int bb = rbase >> 11, s = rbase & 2047;
            const float v0 = acc[i][j][0] + bval;
            const float v1 = acc[i][j][1] + bval;
            const float v2 = acc[i][j][2] + bval;
            const float v3 = acc[i][j][3] + bval;
            if (mode == 1) {
                of32[(size_t)(rbase+0)*HID + col] = v0;
                of32[(size_t)(rbase+1)*HID + col] = v1;
                of32[(size_t)(rbase+2)*HID + col] = v2;
                of32[(size_t)(rbase+3)*HID + col] = v3;
            } else if (z == 2) {
                uint2 ow; ow.x = pk2bf(v0, v1); ow.y = pk2bf(v2, v3);
                *(uint2*)&ovt[(((size_t)bb*NH + hh)*HD + d)*S_LEN + s] = ow;
            } else {
                u16* base = obf + (size_t)z * ((size_t)2*S_LEN*HID);
                base[(((size_t)bb*NH + hh)*S_LEN + s+0)*HD + d] = f2bf(v0);
                base[(((size_t)bb*NH + hh)*S_LEN + s+1)*HD + d] = f2bf(v1);
                base[(((size_t)bb*NH + hh)*S_LEN + s+2)*HD + d] = f2bf(v2);
                base[(((size_t)bb*NH + hh)*S_LEN + s+3)*HD + d] = f2bf(v3);
            }
        }
    }
}

// ---------------------------------------------------------------------------
// Flash attention. Round 7: mask addends as MFMA C-init (no zero-init, no
// post-add on uniform tiles); ONE barrier per tile (epoch-dbuf'd fA/fB);
// max3-fused max tree; pairwise lsum; setprio around MFMA clusters.
// ---------------------------------------------------------------------------
__global__ __launch_bounds__(256) void attn_mfma(
    const u16* __restrict__ Q, const u16* __restrict__ K,
    const u16* __restrict__ Vt, const int* __restrict__ amask,
    const int* __restrict__ gmask, u16* __restrict__ AO)
{
    __shared__ __align__(16) u16 KsA[64*64], VsA[64*64];
    __shared__ __align__(16) u16 KsB[64*64], VsB[64*64];
    __shared__ __align__(16) u16 Ps[4*16*64];
    __shared__ __align__(16) float fAa[64], fBa[64];
    __shared__ __align__(16) float fAb[64], fBb[64];

    const int tid = threadIdx.x;
    const int w  = tid >> 6;
    const int l  = tid & 63;
    const int lx = l & 15;
    const int lg = l >> 4;

    // XCD-aware swizzle: 768 blocks = 8 XCDs x 96
    const int bid = blockIdx.x;
    const int swz = (bid & 7) * 96 + (bid >> 3);
    const int q0 = (swz & 31) * 64;
    const int hb = swz >> 5;
    const int h  = hb % NH;
    const int b  = hb / NH;
    const size_t bh = ((size_t)b*NH + h) * S_LEN;

    const int q_glob = q0 + w*16 + lx;

    short8v aq[2];
    {
        const u16* qp = Q + (bh + q_glob)*HD + lg*8;
        aq[0] = *(const short8v*)(qp);
        aq[1] = *(const short8v*)(qp + 32);
    }
    const int gq = gmask[(size_t)b*S_LEN + q_glob];
    const float* fPa = gq ? fAa : fBa;
    const float* fPb = gq ? fAb : fBb;

    float m_i = NEGV, l_i = 0.f;
    float4v o_acc[4];
    const float4v fzv = {0.f, 0.f, 0.f, 0.f};
    #pragma unroll
    for (int db = 0; db < 4; db++) o_acc[db] = fzv;

    const int str = tid >> 2;
    const int stc = tid & 3;
    const int rb  = str * 128;
    const int sw  = (str & 7) << 4;
    const u16* Kbase = K + bh * HD;
    const u16* Vbase = Vt + (size_t)(b*NH + h) * HD * S_LEN;
    const int psw = (lx & 7) << 4;

    uint4 rk0, rk1, rv0, rv1;
    int ram = 0, rgk = 0;

#define STAGE_REGS(KT) do {                                                   \
    const int kk0_ = (KT) * 64;                                               \
    const u16* kp_ = Kbase + (size_t)(kk0_ + str)*HD + stc*16;                \
    rk0 = *(const uint4*)(kp_); rk1 = *(const uint4*)(kp_ + 8);               \
    const u16* vp_ = Vbase + (size_t)str*S_LEN + kk0_ + stc*16;               \
    rv0 = *(const uint4*)(vp_); rv1 = *(const uint4*)(vp_ + 8);               \
    if (tid < 64) {                                                           \
        ram = amask[(size_t)b*S_LEN + kk0_ + tid];                            \
        rgk = gmask[(size_t)b*S_LEN + kk0_ + tid];                            \
    }                                                                         \
} while(0)

#define WRITE_LDS(KS, VS, FA, FB) do {                                        \
    *(uint4*)((char*)(KS) + rb + ((stc*32)      ^ sw)) = rk0;                 \
    *(uint4*)((char*)(KS) + rb + ((stc*32 + 16) ^ sw)) = rk1;                 \
    *(uint4*)((char*)(VS) + rb + ((stc*32)      ^ sw)) = rv0;                 \
    *(uint4*)((char*)(VS) + rb + ((stc*32 + 16) ^ sw)) = rv1;                 \
    if (tid < 64) {                                                           \
        (FA)[tid] = ram ? 0.f : NEGV;                                         \
        (FB)[tid] = (ram && rgk) ? 0.f : NEGV;                                \
    }                                                                         \
} while(0)

#define COMPUTE(KS, VS, FA, FB, FP, K0) do {                                  \
    /* ---- mask addends become the MFMA C-init ---- */                       \
    float4v sacc[4];                                                          \
    const int adq_ = ((K0) > q0) ? ((K0) - q0) : (q0 - (K0));                 \
    if (adq_ <= 64) {                                                         \
        _Pragma("unroll")                                                     \
        for (int kb = 0; kb < 4; kb++) {                                      \
            float4 fa4 = *(const float4*)&(FA)[kb*16 + lg*4];                 \
            sacc[kb][0]=fa4.x; sacc[kb][1]=fa4.y;                             \
            sacc[kb][2]=fa4.z; sacc[kb][3]=fa4.w;                             \
        }                                                                     \
    } else if (adq_ >= 192) {                                                 \
        _Pragma("unroll")                                                     \
        for (int kb = 0; kb < 4; kb++) {                                      \
            float4 fp4 = *(const float4*)&(FP)[kb*16 + lg*4];                 \
            sacc[kb][0]=fp4.x; sacc[kb][1]=fp4.y;                             \
            sacc[kb][2]=fp4.z; sacc[kb][3]=fp4.w;                             \
        }                                                                     \
    } else {                                                                  \
        _Pragma("unroll")                                                     \
        for (int kb = 0; kb < 4; kb++) {                                      \
            float4 fa4 = *(const float4*)&(FA)[kb*16 + lg*4];                 \
            float4 fb4 = *(const float4*)&(FB)[kb*16 + lg*4];                 \
            const int e_ = q_glob - ((K0) + kb*16 + lg*4);                    \
            _Pragma("unroll")                                                 \
            for (int r = 0; r < 4; r++) {                                     \
                int dd_ = e_ - r; dd_ = dd_ < 0 ? -dd_ : dd_;                 \
                const bool wing_ = (dd_ <= WIN) || gq;                        \
                sacc[kb][r] = wing_ ? (&fa4.x)[r] : (&fb4.x)[r];              \
            }                                                                 \
        }                                                                     \
    }                                                                         \
    __builtin_amdgcn_s_setprio(1);                                            \
    _Pragma("unroll")                                                         \
    for (int kb = 0; kb < 4; kb++) {                                          \
        const int key_ = kb*16 + lx;                                          \
        const int ksw_ = (key_ & 7) << 4;                                     \
        _Pragma("unroll")                                                     \
        for (int ks = 0; ks < 2; ks++) {                                      \
            short8v bk_ = *(const short8v*)((char*)(KS) + key_*128 +          \
                                            ((16*lg + 64*ks) ^ ksw_));        \
            sacc[kb] = __builtin_amdgcn_mfma_f32_16x16x32_bf16(bk_, aq[ks],   \
                                                          sacc[kb], 0, 0, 0); \
        }                                                                     \
    }                                                                         \
    __builtin_amdgcn_s_setprio(0);                                            \
    /* ---- max via v_max3-fusable triples ---- */                            \
    float mloc;                                                               \
    {                                                                         \
        float t0 = fmaxf(fmaxf(sacc[0][0], sacc[0][1]), sacc[0][2]);          \
        float t1 = fmaxf(fmaxf(sacc[0][3], sacc[1][0]), sacc[1][1]);          \
        float t2 = fmaxf(fmaxf(sacc[1][2], sacc[1][3]), sacc[2][0]);          \
        float t3 = fmaxf(fmaxf(sacc[2][1], sacc[2][2]), sacc[2][3]);          \
        float t4 = fmaxf(fmaxf(sacc[3][0], sacc[3][1]), sacc[3][2]);          \
        mloc = fmaxf(fmaxf(fmaxf(t0, t1), t2),                                \
                     fmaxf(fmaxf(t3, t4), sacc[3][3]));                       \
    }                                                                         \
    mloc = fmaxf(mloc, __shfl_xor(mloc, 16));                                 \
    mloc = fmaxf(mloc, __shfl_xor(mloc, 32));                                 \
    if (__any(mloc > m_i + 8.0f)) {                                           \
        const float mnew_ = fmaxf(m_i, mloc);                                 \
        const float sc_ = exp2_fast(m_i - mnew_);                             \
        l_i *= sc_;                                                           \
        _Pragma("unroll")                                                     \
        for (int db = 0; db < 4; db++)                                        \
            _Pragma("unroll")                                                 \
            for (int r = 0; r < 4; r++) o_acc[db][r] *= sc_;                  \
        m_i = mnew_;                                                          \
    }                                                                         \
    float p[4][4];                                                            \
    _Pragma("unroll")                                                         \
    for (int kb = 0; kb < 4; kb++)                                            \
        _Pragma("unroll")                                                     \
        for (int r = 0; r < 4; r++)                                           \
            p[kb][r] = exp2_fast(sacc[kb][r] - m_i);                          \
    {                                                                         \
        float s0 = (p[0][0]+p[0][1]) + (p[0][2]+p[0][3]);                     \
        float s1 = (p[1][0]+p[1][1]) + (p[1][2]+p[1][3]);                     \
        float s2 = (p[2][0]+p[2][1]) + (p[2][2]+p[2][3]);                     \
        float s3 = (p[3][0]+p[3][1]) + (p[3][2]+p[3][3]);                     \
        float lsum = (s0+s1) + (s2+s3);                                       \
        lsum += __shfl_xor(lsum, 16);                                         \
        lsum += __shfl_xor(lsum, 32);                                         \
        l_i += lsum;                                                          \
    }                                                                         \
    _Pragma("unroll")                                                         \
    for (int kb = 0; kb < 4; kb++) {                                          \
        uint2 pw;                                                             \
        pw.x = pk2bf(p[kb][0], p[kb][1]);                                     \
        pw.y = pk2bf(p[kb][2], p[kb][3]);                                     \
        *(uint2*)((char*)Ps + w*2048 + lx*128 + ((kb*32 + lg*8) ^ psw)) = pw; \
    }                                                                         \
    __builtin_amdgcn_s_setprio(1);                                            \
    _Pragma("unroll")                                                         \
    for (int ks = 0; ks < 2; ks++) {                                          \
        short8v pa_ = *(const short8v*)((char*)Ps + w*2048 + lx*128 +         \
                                        ((16*lg + 64*ks) ^ psw));             \
        _Pragma("unroll")                                                     \
        for (int db = 0; db < 4; db++) {                                      \
            const int drow_ = db*16 + lx;                                     \
            short8v bv_ = *(const short8v*)((char*)(VS) + drow_*128 +         \
                                    ((16*lg + 64*ks) ^ ((drow_ & 7) << 4)));  \
            o_acc[db] = __builtin_amdgcn_mfma_f32_16x16x32_bf16(bv_, pa_,     \
                                                          o_acc[db], 0, 0, 0);\
        }                                                                     \
    }                                                                         \
    __builtin_amdgcn_s_setprio(0);                                            \
} while(0)

    // prologue: stage tile 0 into epoch A
    STAGE_REGS(0);
    WRITE_LDS(KsA, VsA, fAa, fBa);
    __syncthreads();

    // ONE barrier per tile: WRITE(other-epoch) is disjoint from COMPUTE(cur),
    // and each wave's COMPUTE(cur) precedes its WRITE(other) in program order,
    // so the post-WRITE barrier also fences the next overwrite of `cur`.
    for (int kt = 0; kt < S_LEN/64; kt += 2) {
        STAGE_REGS(kt+1);
        COMPUTE(KsA, VsA, fAa, fBa, fPa, kt*64);
        WRITE_LDS(KsB, VsB, fAb, fBb);
        __syncthreads();
        {
            const int kn = (kt+2 < S_LEN/64) ? (kt+2) : (S_LEN/64 - 1);
            STAGE_REGS(kn);
        }
        COMPUTE(KsB, VsB, fAb, fBb, fPb, (kt+1)*64);
        WRITE_LDS(KsA, VsA, fAa, fBa);
        __syncthreads();
    }

#undef STAGE_REGS
#undef WRITE_LDS
#undef COMPUTE

    // epilogue
    {
        const float inv = 1.f / l_i;
        u16* op = AO + ((size_t)b*S_LEN + q_glob)*HID + h*HD + lg*4;
        #pragma unroll
        for (int db = 0; db < 4; db++) {
            uint2 ow;
            ow.x = pk2bf(o_acc[db][0]*inv, o_acc[db][1]*inv);
            ow.y = pk2bf(o_acc[db][2]*inv, o_acc[db][3]*inv);
            *(uint2*)(op + db*16) = ow;
        }
    }
}

// ---------------------------------------------------------------------------
extern "C" void kernel_launch(void* const* d_in, const int* in_sizes, int n_in,
                              void* d_out, int out_size, void* d_ws, size_t ws_size,
                              hipStream_t stream)
{
    const float* hidden = (const float*)d_in[0];
    const int*   amask  = (const int*)d_in[1];
    const int*   gmask  = (const int*)d_in[2];
    const float* Wq = (const float*)d_in[3];
    const float* bq = (const float*)d_in[4];
    const float* Wk = (const float*)d_in[5];
    const float* bk = (const float*)d_in[6];
    const float* Wv = (const float*)d_in[7];
    const float* bv = (const float*)d_in[8];
    const float* Wo = (const float*)d_in[9];
    const float* bo = (const float*)d_in[10];
    float* out = (float*)d_out;

    char* ws = (char*)d_ws;
    const size_t NTOK = (size_t)2 * S_LEN * HID;   // 3,145,728
    u16* hbf   = (u16*)(ws);
    u16* w4    = (u16*)(ws + 6291456);
    u16* qkvbf = (u16*)(ws + 11010048);            // Q, K (2 x NTOK)
    u16* vtbf  = (u16*)(ws + 29884416);            // V transposed (B,nh,hd,S)
    u16* aobf  = (u16*)(ws + 36175872);

    convert_inputs<<<dim3(1536, 5), 256, 0, stream>>>(hidden, Wq, Wk, Wv, Wo, hbf, w4);

    gemm_mfma<<<dim3(32, 6, 3), 256, 0, stream>>>(hbf, w4, bq, bk, bv, qkvbf, vtbf, nullptr, 0);

    u16* Qbf = qkvbf;
    u16* Kbf = qkvbf + NTOK;

    attn_mfma<<<dim3(768), 256, 0, stream>>>(Qbf, Kbf, vtbf, amask, gmask, aobf);

    gemm_mfma<<<dim3(32, 6), 256, 0, stream>>>(aobf, w4, bo, nullptr, nullptr, nullptr, nullptr, out, 1);
}